// Round 12
// baseline (621.353 us; speedup 1.0000x reference)
//
#include <hip/hip_runtime.h>
#include <cmath>

#define NANCH 36864
#define NPRE 6000
#define NPOST 300

// ---- output (float) offsets ----
#define LOCS_OFF   0
#define SCORES_OFF 294912
#define ROIS_OFF   442368
#define RIDX_OFF   444768
#define ANCH_OFF   445368

// ---- workspace byte offsets ----
#define WT_OFF      0ull          // fallback: 9*512*512*4 = 9437184 fp32 wt
#define WTH_OFF     0ull          // mfma: f16 hi 9*512*512*2 = 4718592
#define WTL_OFF     4718592ull    // mfma: f16 lo (scaled 2^10)
#define PREFIX_OFF  2097152ull    // 2*65536*4 (inside dead WT region)
#define PREFIXM_OFF 2621440ull
#define SORTED_OFF  3145728ull
#define MASK_OFF    0ull          // reuse after fixup
#define H_OFF       9437184ull    // 2*512*4096*4  = 16777216
#define BOXES_OFF   26214400ull
#define W54_OFF     26214400ull
#define KEYS_OFF    27394048ull
#define HIST_OFF    27983872ull
#define SKEYS_OFF   28631168ull
#define SBOXES_OFF  28727168ull
#define VMASK_OFF   29033856ull
// MFMA-path extra regions (only if ws_size >= 46137344):
#define XTH_OFF     29360128ull   // x f16 hi: 2*64*16*64*32*2 = 8388608
#define XTL_OFF     37748736ull   // x f16 lo (scaled 2^10)
#define WS_NEED_MFMA 46137344ull

typedef _Float16 half8 __attribute__((ext_vector_type(8)));
typedef float floatx4 __attribute__((ext_vector_type(4)));

__device__ __forceinline__ void load_lds16(const float* g, float* l) {
#if __has_builtin(__builtin_amdgcn_global_load_lds)
  __builtin_amdgcn_global_load_lds(
      (const __attribute__((address_space(1))) void*)g,
      (__attribute__((address_space(3))) void*)l, 16, 0, 0);
#else
  int lane = threadIdx.x & 63;
  float4 v = *(const float4*)g;
  *(float4*)((char*)l + lane * 16) = v;
#endif
}

__device__ __forceinline__ void load_lds16g(const void* g, void* l) {
#if __has_builtin(__builtin_amdgcn_global_load_lds)
  __builtin_amdgcn_global_load_lds(
      (const __attribute__((address_space(1))) void*)g,
      (__attribute__((address_space(3))) void*)l, 16, 0, 0);
#else
  int lane = threadIdx.x & 63;
  float4 v = *(const float4*)g;
  *(float4*)((char*)l + lane * 16) = v;
#endif
}

// =====================================================================
// prep (FALLBACK path): fused weight transposes (R10/R11-verified)
// =====================================================================
__global__ __launch_bounds__(1024) void prep_kernel(
    const float* __restrict__ w, float* __restrict__ wt,
    const float* __restrict__ lw, const float* __restrict__ sw,
    float* __restrict__ w54p) {
  __shared__ float lds[9][32][33];
  if (blockIdx.x < 256) {
    int tx = threadIdx.x & 31;
    int ty = threadIdx.x >> 5;
    int ci0 = (blockIdx.x & 15) * 32;
    int co0 = (blockIdx.x >> 4) * 32;
    const float* src = w + ((size_t)(co0 + ty) * 512 + (ci0 + tx)) * 9;
#pragma unroll
    for (int k = 0; k < 9; k++) lds[k][tx][ty] = src[k];
    __syncthreads();
#pragma unroll
    for (int k = 0; k < 9; k++) {
      wt[((size_t)k * 512 + (ci0 + ty)) * 512 + co0 + tx] = lds[k][ty][tx];
    }
  } else {
    int t = (blockIdx.x - 256) * 1024 + threadIdx.x;
    int k = t >> 6, co = t & 63;
    float v = 0.f;
    if (co < 36) v = lw[(size_t)co * 512 + k];
    else if (co < 54) v = sw[(size_t)(co - 36) * 512 + k];
    w54p[t] = v;
  }
}

// =====================================================================
// prep16 (MFMA path): conv1 weights -> f16 hi/lo.
// R9 layout (kept): [9 k][4 co_tile][16 cs][4 g][128 co][8 ci] f16.
// R11: this layout now also serves DIRECT global->register W-frag
// loads in conv (each lane's frag = one contiguous 16B).
// =====================================================================
__global__ __launch_bounds__(1024) void prep16_kernel(
    const float* __restrict__ w, _Float16* __restrict__ wth,
    _Float16* __restrict__ wtl, const float* __restrict__ lw,
    const float* __restrict__ sw, float* __restrict__ w54p) {
  if (blockIdx.x < 256) {
    int tx = threadIdx.x & 31;              // ci within 32-block
    int ty = threadIdx.x >> 5;              // co within 32-block
    int ci0 = (blockIdx.x & 15) * 32;
    int co0 = (blockIdx.x >> 4) * 32;
    int ci = ci0 + tx, co = co0 + ty;
    const float* src = w + ((size_t)co * 512 + ci) * 9;
    int cot = co >> 7, coin = co & 127;
    int cs = ci >> 5, gg = (ci >> 3) & 3, cii = ci & 7;
    size_t obase = ((((size_t)cot) * 16 + cs) * 4 + gg) * 1024 +
                   (size_t)coin * 8 + cii;
#pragma unroll
    for (int k = 0; k < 9; k++) {
      float v = src[k];
      _Float16 h = (_Float16)v;
      _Float16 l = (_Float16)((v - (float)h) * 1024.f);
      size_t o = (size_t)k * 262144 + obase;
      wth[o] = h;
      wtl[o] = l;
    }
  } else {
    int t = (blockIdx.x - 256) * 1024 + threadIdx.x;
    int k = t >> 6, co = t & 63;
    float v = 0.f;
    if (co < 36) v = lw[(size_t)co * 512 + k];
    else if (co < 54) v = sw[(size_t)(co - 36) * 512 + k];
    w54p[t] = v;
  }
}

// =====================================================================
// prepx (MFMA path): x[n][ci][y][px] -> xt_{h,l}[n][y][cs][g][px][8ci].
// R9 layout (kept): g-major, 16B lane stride in conv LDS.
// =====================================================================
__global__ __launch_bounds__(256) void prepx_kernel(
    const float* __restrict__ x, _Float16* __restrict__ xth,
    _Float16* __restrict__ xtl) {
  __shared__ float xs[32][65];
  int b = blockIdx.x;
  int cs = b & 15, ny = b >> 4;
  int n = ny >> 6, y = ny & 63;
  int tid = threadIdx.x;
  const float* xb = x + ((size_t)n << 21) + (y << 6);
#pragma unroll
  for (int p = 0; p < 8; p++) {
    int c = p * 4 + (tid >> 6);
    xs[c][tid & 63] = xb[((size_t)(cs * 32 + c) << 12) + (tid & 63)];
  }
  __syncthreads();
  int px = tid & 63, gx = tid >> 6;        // 4 groups x 64 px
  unsigned int hw[4], lw2[4];
#pragma unroll
  for (int j = 0; j < 4; j++) {
    float v0 = xs[gx * 8 + 2 * j][px], v1 = xs[gx * 8 + 2 * j + 1][px];
    _Float16 h0 = (_Float16)v0, h1 = (_Float16)v1;
    _Float16 l0 = (_Float16)((v0 - (float)h0) * 1024.f);
    _Float16 l1 = (_Float16)((v1 - (float)h1) * 1024.f);
    hw[j] = (unsigned int)__builtin_bit_cast(unsigned short, h0) |
            ((unsigned int)__builtin_bit_cast(unsigned short, h1) << 16);
    lw2[j] = (unsigned int)__builtin_bit_cast(unsigned short, l0) |
             ((unsigned int)__builtin_bit_cast(unsigned short, l1) << 16);
  }
  size_t o = (size_t)b * 2048 + (size_t)gx * 512 + (size_t)px * 8;
  uint4 hv; hv.x = hw[0]; hv.y = hw[1]; hv.z = hw[2]; hv.w = hw[3];
  uint4 lv; lv.x = lw2[0]; lv.y = lw2[1]; lv.z = lw2[2]; lv.w = lw2[3];
  *(uint4*)(xth + o) = hv;
  *(uint4*)(xtl + o) = lv;
}

// =====================================================================
// conv1 MFMA v3 (R11, resubmitted after infra failure): W staging
// REMOVED — W frags load global->reg directly (each lane's frag =
// contiguous 16B in the R9 [g][co][8ci] layout). Per-(cs,tap) W
// working set is 32KB/XCD and all blocks sweep (cs,tap) in lockstep
// -> L2-resident; re-reads never hit HBM. Barriers per block drop
// ~290 -> 33 (2 per cs; none between taps since X LDS is read-only
// during taps). Same W values from same addresses, same frag/MFMA
// order as R10 -> bit-identical h. LDS 25344B (X only).
// =====================================================================
__global__ __launch_bounds__(256, 3) void conv1_mfma_kernel(
    const _Float16* __restrict__ xth, const _Float16* __restrict__ xtl,
    const _Float16* __restrict__ wth, const _Float16* __restrict__ wtl,
    const float* __restrict__ bias, float* __restrict__ hout) {
  __shared__ __align__(16) _Float16 sXh[6336];   // [3 yr][4 g][66 row][8]
  __shared__ __align__(16) _Float16 sXl[6336];
  int mb = blockIdx.x;
  int n = mb >> 6, y = mb & 63;
  int co0 = blockIdx.y << 7;
  int tid = threadIdx.x;
  int wv = tid >> 6, lane = tid & 63;
  int m15 = lane & 15, g = lane >> 4;

  floatx4 accm[2][4], accl[2][4];
#pragma unroll
  for (int ct = 0; ct < 2; ct++)
#pragma unroll
    for (int pt = 0; pt < 4; pt++) {
      accm[ct][pt] = (floatx4){0.f, 0.f, 0.f, 0.f};
      accl[ct][pt] = (floatx4){0.f, 0.f, 0.f, 0.f};
    }

  // zero X LDS once: pad rows 0/65 of each g-group + invalid-yr slices
  for (int t2 = tid; t2 < 3168; t2 += 256) {
    ((unsigned int*)sXh)[t2] = 0u;
    ((unsigned int*)sXl)[t2] = 0u;
  }
  __syncthreads();

  bool yv0 = (y > 0), yv2 = (y < 63);
  // per-lane W base: co = wv*32 + ct*16 + m15 (ct adds 128 halves)
  size_t wlanebase = (size_t)(co0 >> 7) * 65536 + (size_t)g * 1024 +
                     (size_t)(((wv << 5) + m15) << 3);

  for (int cs = 0; cs < 16; cs++) {
    if (cs) __syncthreads();     // all waves done reading prev-cs X
    // ---- X DMA: 24 wave-DMAs (6/wave): (yr, part, g) x 1KB linear ----
    {
      int base = wv * 6;
#pragma unroll
      for (int i = 0; i < 6; i++) {
        int idx = base + i;                 // 0..23
        int yr = idx >> 3, rem = idx & 7;
        int part = rem >> 2, d = rem & 3;   // d = g-group
        int ys = y + yr - 1;
        if (ys >= 0 && ys < 64) {           // wave-uniform
          const _Float16* s =
              (part ? xtl : xth) +
              ((((size_t)(n * 64 + ys)) * 16 + cs) << 11) + (d << 9) +
              (lane << 3);
          _Float16* dst = (part ? sXl : sXh) + yr * 2112 + d * 528 + 8;
          load_lds16g(s, dst);
        }
      }
    }
    __syncthreads();             // X ready (vmcnt drained before barrier)

    const _Float16* whp = wth + wlanebase + (size_t)cs * 4096;
    const _Float16* wlp = wtl + wlanebase + (size_t)cs * 4096;
#pragma unroll
    for (int ky = 0; ky < 3; ky++) {
      if (ky == 0 && !yv0) continue;        // block-uniform: zero slice
      if (ky == 2 && !yv2) continue;
#pragma unroll
      for (int kx = 0; kx < 3; kx++) {
        int tap = ky * 3 + kx;
        size_t to = (size_t)tap * 262144;
        // ---- W frags: direct global->reg (L2-resident) ----
        half8 Ah[2], Al[2], Bh[4], Bl[4];
        Ah[0] = *(const half8*)(whp + to);
        Ah[1] = *(const half8*)(whp + to + 128);
        Al[0] = *(const half8*)(wlp + to);
        Al[1] = *(const half8*)(wlp + to + 128);
        // ---- B frags from LDS (16B lane stride: conflict-free) ----
#pragma unroll
        for (int pt = 0; pt < 4; pt++) {
          int bo = ky * 2112 + g * 528 + (((pt << 4) + m15 + kx) << 3);
          Bh[pt] = *(const half8*)(sXh + bo);
          Bl[pt] = *(const half8*)(sXl + bo);
        }
#pragma unroll
        for (int ct = 0; ct < 2; ct++)
#pragma unroll
          for (int pt = 0; pt < 4; pt++) {
            accm[ct][pt] = __builtin_amdgcn_mfma_f32_16x16x32_f16(
                Ah[ct], Bh[pt], accm[ct][pt], 0, 0, 0);
            accl[ct][pt] = __builtin_amdgcn_mfma_f32_16x16x32_f16(
                Ah[ct], Bl[pt], accl[ct][pt], 0, 0, 0);
            accl[ct][pt] = __builtin_amdgcn_mfma_f32_16x16x32_f16(
                Al[ct], Bh[pt], accl[ct][pt], 0, 0, 0);
          }
      }
    }
  }

#pragma unroll
  for (int ct = 0; ct < 2; ct++)
#pragma unroll
    for (int pt = 0; pt < 4; pt++) {
#pragma unroll
      for (int r = 0; r < 4; r++) {
        int co = co0 + (wv << 5) + (ct << 4) + (g << 2) + r;
        float v = accm[ct][pt][r] + accl[ct][pt][r] * 0.0009765625f +
                  bias[co];
        hout[((size_t)(n * 512 + co) << 12) + (y << 6) + (pt << 4) + m15] =
            fmaxf(v, 0.f);
      }
    }
}

// =====================================================================
// conv1 v9 (FALLBACK, proven): fp32 3x3 512->512 + bias + ReLU.
// =====================================================================
__global__ __launch_bounds__(256) void conv1_kernel(
    const float* __restrict__ x, const float* __restrict__ wt,
    const float* __restrict__ bias, float* __restrict__ hout) {
  __shared__ __align__(16) float smem[10752];
  int mb = blockIdx.x;
  int n = mb >> 6, y = mb & 63;
  int co0 = blockIdx.y << 7;
  int tid = threadIdx.x;
  int team = tid >> 7;
  int tl = tid & 127;
  int cibase = team << 8;
  float* Asb = smem + team * 768;
  float* Bsb = smem + 1536 + team * 4608;
  int tx = tl & 7, ty = tl >> 3;
  int x0 = tx << 3;

  float acc[8][8];
#pragma unroll
  for (int j = 0; j < 8; j++)
#pragma unroll
    for (int i = 0; i < 8; i++) acc[j][i] = 0.f;

  const float* xb = x + ((size_t)n << 21);

  if (y == 0) {
    for (int t2 = tl; t2 < 256; t2 += 128) Asb[t2] = 0.f;
  }
  if (y == 63) {
    for (int t2 = tl; t2 < 256; t2 += 128) Asb[512 + t2] = 0.f;
  }

  int wv = tl >> 6;
  int lane = tl & 63;
  int lrow = lane >> 5;
  int lcol = (lane & 31) << 2;
  int aci = lane >> 4;
  int aoff = (lane & 15) << 2;

  for (int cc = 0; cc < 256; cc += 4) {
    int ci0 = cibase + cc;
    for (int yr = wv; yr < 3; yr += 2) {
      int ys = y + yr - 1;
      if (ys >= 0 && ys < 64) {
        const float* g =
            xb + (((size_t)(ci0 + aci)) << 12) + (ys << 6) + aoff;
        load_lds16(g, &Asb[yr << 8]);
      }
    }
    for (int i = 0; i < 9; i++) {
      int r0 = i * 4 + wv * 2;
      int row = r0 + lrow;
      int kk = row >> 2, ci = row & 3;
      const float* g = wt + (((size_t)(kk << 9)) + ci0 + ci) * 512 + co0 + lcol;
      load_lds16(g, &Bsb[r0 << 7]);
    }
    __syncthreads();
    for (int k = 0; k < 4; k++) {
#pragma unroll
      for (int ky = 0; ky < 3; ky++) {
        const float* arr = &Asb[((ky << 2) + k) << 6];
        float w10[10];
        w10[0] = (tx == 0) ? 0.f : arr[x0 - 1];
        float4 a0 = *(const float4*)&arr[x0];
        float4 a1 = *(const float4*)&arr[x0 + 4];
        w10[1] = a0.x; w10[2] = a0.y; w10[3] = a0.z; w10[4] = a0.w;
        w10[5] = a1.x; w10[6] = a1.y; w10[7] = a1.z; w10[8] = a1.w;
        w10[9] = (tx == 7) ? 0.f : arr[x0 + 8];
#pragma unroll
        for (int kx = 0; kx < 3; kx++) {
          int kk = ky * 3 + kx;
          const float* br = &Bsb[(((kk << 2) + k) << 7) + (ty << 3)];
          float4 b0 = *(const float4*)br;
          float4 b1 = *(const float4*)(br + 4);
          float bb[8] = {b0.x, b0.y, b0.z, b0.w, b1.x, b1.y, b1.z, b1.w};
#pragma unroll
          for (int j = 0; j < 8; j++)
#pragma unroll
            for (int dx = 0; dx < 8; dx++)
              acc[j][dx] = fmaf(w10[kx + dx], bb[j], acc[j][dx]);
        }
      }
    }
    __syncthreads();
  }

  if (team == 1) {
#pragma unroll
    for (int j = 0; j < 8; j++) {
      *(float4*)&smem[tl * 68 + (j << 3)] = *(float4*)&acc[j][0];
      *(float4*)&smem[tl * 68 + (j << 3) + 4] = *(float4*)&acc[j][4];
    }
  }
  __syncthreads();
  if (team == 0) {
#pragma unroll
    for (int j = 0; j < 8; j++) {
      int co = co0 + (ty << 3) + j;
      float bv = bias[co];
      float4 p0 = *(float4*)&smem[tl * 68 + (j << 3)];
      float4 p1 = *(float4*)&smem[tl * 68 + (j << 3) + 4];
      float4 v0, v1;
      v0.x = fmaxf((acc[j][0] + p0.x) + bv, 0.f);
      v0.y = fmaxf((acc[j][1] + p0.y) + bv, 0.f);
      v0.z = fmaxf((acc[j][2] + p0.z) + bv, 0.f);
      v0.w = fmaxf((acc[j][3] + p0.w) + bv, 0.f);
      v1.x = fmaxf((acc[j][4] + p1.x) + bv, 0.f);
      v1.y = fmaxf((acc[j][5] + p1.y) + bv, 0.f);
      v1.z = fmaxf((acc[j][6] + p1.z) + bv, 0.f);
      v1.w = fmaxf((acc[j][7] + p1.w) + bv, 0.f);
      float* o = &hout[(((size_t)(n * 512 + co)) << 12) + (y << 6) + x0];
      *(float4*)o = v0;
      *(float4*)(o + 4) = v1;
    }
  }
}

// =====================================================================
// heads v2 (proven): tiled GEMM M=64p x N=54 x K=512.
// =====================================================================
__global__ __launch_bounds__(256) void heads_kernel(
    const float* __restrict__ h, const float* __restrict__ w54p,
    const float* __restrict__ loc_b, const float* __restrict__ score_b,
    float* __restrict__ out) {
  __shared__ __align__(16) float hs[32 * 64];
  __shared__ __align__(16) float wsd[32 * 64];
  __shared__ float sacc[64 * 65];
  int n = blockIdx.x >> 6;
  int p0 = (blockIdx.x & 63) << 6;
  int tid = threadIdx.x;
  int txp = tid & 63;
  int tw = tid >> 6;
  float acc[16];
#pragma unroll
  for (int j = 0; j < 16; j++) acc[j] = 0.f;
  const float* hb = h + ((size_t)n * 512) * 4096 + p0;
  for (int k0 = 0; k0 < 512; k0 += 32) {
    for (int t = tid; t < 512; t += 256) {
      int r = t >> 4, l = (t & 15) << 2;
      *(float4*)&hs[(r << 6) + l] =
          *(const float4*)&hb[(((size_t)(k0 + r)) << 12) + l];
      *(float4*)&wsd[(r << 6) + l] =
          *(const float4*)&w54p[((k0 + r) << 6) + l];
    }
    __syncthreads();
    for (int k = 0; k < 32; k++) {
      float hv = hs[(k << 6) + txp];
      const float* wr = &wsd[(k << 6) + (tw << 4)];
#pragma unroll
      for (int u = 0; u < 4; u++) {
        float4 wv = *(const float4*)(wr + (u << 2));
        acc[u * 4 + 0] = fmaf(hv, wv.x, acc[u * 4 + 0]);
        acc[u * 4 + 1] = fmaf(hv, wv.y, acc[u * 4 + 1]);
        acc[u * 4 + 2] = fmaf(hv, wv.z, acc[u * 4 + 2]);
        acc[u * 4 + 3] = fmaf(hv, wv.w, acc[u * 4 + 3]);
      }
    }
    __syncthreads();
  }
#pragma unroll
  for (int j = 0; j < 16; j++) sacc[(tw * 16 + j) * 65 + txp] = acc[j];
  __syncthreads();
  for (int t = tid; t < 64 * 54; t += 256) {
    int p = t / 54, c = t - p * 54;
    float v = sacc[c * 65 + p];
    int gp = (n << 12) + p0 + p;
    if (c < 36) out[LOCS_OFF + (size_t)gp * 36 + c] = v + loc_b[c];
    else out[SCORES_OFF + (size_t)gp * 18 + (c - 36)] = v + score_b[c - 36];
  }
}

// =====================================================================
// Decode (anchors fused + hist fused; valid-only hist atomics, R5)
// =====================================================================
__global__ void decode_kernel(const float* __restrict__ out_ro,
                              const int* __restrict__ pimh,
                              const int* __restrict__ pimw,
                              float* __restrict__ boxes,
                              unsigned long long* __restrict__ keys,
                              unsigned int* __restrict__ hist,
                              float* __restrict__ out) {
  int t = blockIdx.x * 256 + threadIdx.x;
  int n = t / NANCH, k = t - n * NANCH;
  float imh = (float)pimh[0], imw = (float)pimw[0];

  int a = k % 9, pos = k / 9;
  int jj = pos & 63, ii = pos >> 6;
  int ridx = a / 3, sidx = a % 3;
  double r = (ridx == 0) ? 0.5 : ((ridx == 1) ? 1.0 : 2.0);
  double s = (sidx == 0) ? 8.0 : ((sidx == 1) ? 16.0 : 32.0);
  double ahh = 16.0 * s * sqrt(r);
  double aww = 16.0 * s * sqrt(1.0 / r);
  float b0 = (float)(8.0 - ahh / 2.0), b1 = (float)(8.0 - aww / 2.0);
  float b2 = (float)(8.0 + ahh / 2.0), b3 = (float)(8.0 + aww / 2.0);
  float sy = (float)(ii * 16), sx = (float)(jj * 16);
  float a0 = sy + b0, a1 = sx + b1, a2 = sy + b2, a3 = sx + b3;
  if (n == 0) {
    float* o = out + ANCH_OFF + (size_t)k * 4;
    o[0] = a0; o[1] = a1; o[2] = a2; o[3] = a3;
  }

  const float* loc = out_ro + LOCS_OFF + (size_t)t * 4;
  const float* sc = out_ro + SCORES_OFF + (size_t)t * 2;
  float ah = __fsub_rn(a2, a0), aw = __fsub_rn(a3, a1);
  float acy = __fadd_rn(a0, 0.5f * ah), acx = __fadd_rn(a1, 0.5f * aw);
  float dy = loc[0], dx = loc[1], dh = loc[2], dw = loc[3];
  float cy = __fadd_rn(__fmul_rn(dy, ah), acy);
  float cx = __fadd_rn(__fmul_rn(dx, aw), acx);
  float hh = __fmul_rn(expf(dh), ah);
  float ww = __fmul_rn(expf(dw), aw);
  float y1 = __fsub_rn(cy, 0.5f * hh), x1 = __fsub_rn(cx, 0.5f * ww);
  float y2 = __fadd_rn(cy, 0.5f * hh), x2 = __fadd_rn(cx, 0.5f * ww);
  y1 = fminf(fmaxf(y1, 0.f), imh); x1 = fminf(fmaxf(x1, 0.f), imw);
  y2 = fminf(fmaxf(y2, 0.f), imh); x2 = fminf(fmaxf(x2, 0.f), imw);
  bool valid = (__fsub_rn(y2, y1) >= 16.f) && (__fsub_rn(x2, x1) >= 16.f);
  float s0 = sc[0], s1 = sc[1];
  float m = fmaxf(s0, s1);
  float e0 = expf(__fsub_rn(s0, m)), e1 = expf(__fsub_rn(s1, m));
  float fg = __fdiv_rn(e1, __fadd_rn(e0, e1));
  float score = valid ? fg : -INFINITY;
  unsigned int u = __float_as_uint(score);
  unsigned int ord = (u & 0x80000000u) ? ~u : (u | 0x80000000u);
  unsigned long long key =
      ((unsigned long long)(~ord) << 16) | (unsigned long long)(k & 0xFFFF);
  float4 b4; b4.x = y1; b4.y = x1; b4.z = y2; b4.w = x2;
  *(float4*)(boxes + (size_t)t * 4) = b4;
  keys[t] = key;
  if (valid)
    atomicAdd(&hist[((size_t)n << 16) + (unsigned int)(key >> 32)], 1u);
}

// =====================================================================
// Full exclusive prefix over 65536 buckets (per batch), uint4-vectorized
// =====================================================================
__global__ __launch_bounds__(1024) void scanfull_kernel(
    const unsigned int* __restrict__ hist, unsigned int* __restrict__ prefix,
    unsigned int* __restrict__ prefix_mut) {
  int n = blockIdx.x;
  const uint4* h4 = (const uint4*)(hist + ((size_t)n << 16));
  uint4* pf4 = (uint4*)(prefix + ((size_t)n << 16));
  uint4* pm4 = (uint4*)(prefix_mut + ((size_t)n << 16));
  __shared__ unsigned int ps[1024];
  int tid = threadIdx.x;
  int base4 = tid << 4;
  uint4 vals[16];
  unsigned int s = 0;
#pragma unroll
  for (int i = 0; i < 16; i++) {
    vals[i] = h4[base4 + i];
    s += vals[i].x + vals[i].y + vals[i].z + vals[i].w;
  }
  ps[tid] = s;
  __syncthreads();
  for (int off = 1; off < 1024; off <<= 1) {
    unsigned int v = ps[tid];
    unsigned int add = (tid >= off) ? ps[tid - off] : 0u;
    __syncthreads();
    ps[tid] = v + add;
    __syncthreads();
  }
  unsigned int run = ps[tid] - s;
#pragma unroll
  for (int i = 0; i < 16; i++) {
    uint4 hv = vals[i];
    uint4 pv;
    pv.x = run; run += hv.x;
    pv.y = run; run += hv.y;
    pv.z = run; run += hv.z;
    pv.w = run; run += hv.w;
    pf4[base4 + i] = pv;
    pm4[base4 + i] = pv;
  }
}

// =====================================================================
// Scatter into bucket-sorted order (skip invalid keys, R5)
// =====================================================================
__global__ void scatter_kernel(const unsigned long long* __restrict__ keys,
                               unsigned int* __restrict__ prefix_mut,
                               unsigned long long* __restrict__ sorted) {
  int t = blockIdx.x * 256 + threadIdx.x;
  int n = t / NANCH;
  unsigned long long key = keys[t];
  unsigned int b = (unsigned int)(key >> 32);
  if (b >= 0xFF80u) return;          // invalid (-inf) keys: never scattered
  unsigned int pos = atomicAdd(&prefix_mut[((size_t)n << 16) + b], 1u);
  if (pos < 8192) sorted[((size_t)n << 13) + pos] = key;
}

// =====================================================================
// Fixup: exact rank within bucket -> final sorted top-6000 + boxes
// =====================================================================
__global__ void fixup_kernel(const unsigned long long* __restrict__ sorted,
                             const unsigned int* __restrict__ prefix,
                             const unsigned int* __restrict__ hist,
                             const float* __restrict__ boxes,
                             unsigned long long* __restrict__ skeys,
                             float* __restrict__ sboxes) {
  int t = blockIdx.x * 256 + threadIdx.x;
  int n = t / 7168;
  int s = t - n * 7168;
  const unsigned long long* srt = sorted + ((size_t)n << 13);
  unsigned long long key = srt[s];
  unsigned int hi = (unsigned int)(key >> 16);
  if (hi >= 0xFF800000u) {
    if (s < NPRE) skeys[(size_t)n * NPRE + s] = key;
    return;
  }
  unsigned int b = (unsigned int)(key >> 32);
  unsigned int st = prefix[((size_t)n << 16) + b];
  if (st >= (unsigned)NPRE) return;
  unsigned int cnt = hist[((size_t)n << 16) + b];
  unsigned int r = 0;
  if (cnt > 1) {
    for (unsigned int j = 0; j < cnt; j++) r += (srt[st + j] < key) ? 1u : 0u;
  }
  unsigned int pos = st + r;
  if (pos < (unsigned)NPRE) {
    skeys[(size_t)n * NPRE + pos] = key;
    int k = (int)(key & 0xFFFFull);
    float4 bx = *(const float4*)(boxes + (((size_t)n * NANCH) + k) * 4);
    *(float4*)(sboxes + ((size_t)n * NPRE + pos) * 4) = bx;
  }
}

// =====================================================================
// NMS phase A: upper-triangle pairwise suppression bitmask (R3-proven)
// =====================================================================
__global__ __launch_bounds__(64) void nms_mask_kernel(
    const float* __restrict__ sboxes,
    const unsigned long long* __restrict__ skeys,
    unsigned long long* __restrict__ vmask,
    unsigned long long* __restrict__ mask) {
  int n = blockIdx.z;
  int ib = blockIdx.x, jb = blockIdx.y;
  if (jb < ib) return;
  int lane = threadIdx.x;
  __shared__ __align__(16) float jbox[64][4];
  int j = jb * 64 + lane;
  float4 bj4 = (j < NPRE)
                   ? *(const float4*)(sboxes + ((size_t)n * NPRE + j) * 4)
                   : float4{0.f, 0.f, 0.f, 0.f};
  *(float4*)jbox[lane] = bj4;
  __syncthreads();
  if (jb == ib) {
    int idx = ib * 64 + lane;
    bool ok = false;
    if (idx < NPRE) {
      unsigned int khi = (unsigned int)(skeys[(size_t)n * NPRE + idx] >> 16);
      ok = khi < 0xFF800000u;
    }
    unsigned long long m = __ballot(ok);
    if (lane == 0) vmask[(size_t)n * 94 + ib] = m;
  }
  int i = ib * 64 + lane;
  if (i >= NPRE) return;
  float4 bi = *(const float4*)(sboxes + ((size_t)n * NPRE + i) * 4);
  float ay1 = bi.x, ax1 = bi.y, ay2 = bi.z, ax2 = bi.w;
  float areaA = __fmul_rn(__fsub_rn(ay2, ay1), __fsub_rn(ax2, ax1));
  unsigned long long bits = 0ull;
#pragma unroll 8
  for (int l = 0; l < 64; l++) {
    float4 bj = *(const float4*)jbox[l];
    float ty1 = fmaxf(ay1, bj.x), tx1 = fmaxf(ax1, bj.y);
    float ty2 = fminf(ay2, bj.z), tx2 = fminf(ax2, bj.w);
    float wh0 = fmaxf(__fsub_rn(ty2, ty1), 0.f);
    float wh1 = fmaxf(__fsub_rn(tx2, tx1), 0.f);
    float inter = __fmul_rn(wh0, wh1);
    float areaB = __fmul_rn(__fsub_rn(bj.z, bj.x), __fsub_rn(bj.w, bj.y));
    float den = __fadd_rn(__fsub_rn(__fadd_rn(areaA, areaB), inter), 1e-9f);
    float iou = __fdiv_rn(inter, den);
    if (iou > 0.7f) bits |= (1ull << l);
  }
  mask[((size_t)n * NPRE + i) * 94 + jb] = bits;
}

// =====================================================================
// NMS phase B (R8-proven): cooperative L2 warm + serial greedy loop.
// Do not add in-loop load-consuming state (R9 lesson).
// =====================================================================
#define WARM_ROWS 2048

__global__ __launch_bounds__(1024) void nms_reduce_kernel(
    const unsigned long long* __restrict__ mask,
    const unsigned long long* __restrict__ vmask,
    const float* __restrict__ sboxes, float* __restrict__ out) {
  int n = blockIdx.x;
  __shared__ int kept[NPOST];

  // ---- cooperative L2 warm: rows 0..WARM_ROWS-1 of this batch's mask
  {
    const ulonglong2* m2 =
        (const ulonglong2*)(mask + (size_t)n * NPRE * 94);
    unsigned long long accw = 0;
    const int total = WARM_ROWS * 94 / 2;    // 96256 x 16B = 1.54 MB
    for (int i = threadIdx.x; i < total; i += 1024) {
      ulonglong2 v = m2[i];
      accw ^= v.x ^ v.y;
    }
    asm volatile("" :: "v"(accw));           // keep loads live (rule #17)
  }
  __syncthreads();
  if (threadIdx.x >= 64) return;             // wave 0 only past this point

  int lane = threadIdx.x;

  unsigned long long rlo = ~vmask[(size_t)n * 94 + lane];
  unsigned long long rhi = (64 + lane < 94) ? ~vmask[(size_t)n * 94 + 64 + lane]
                                            : ~0ull;
  int count = 0;
  for (int c = 0; c < 94 && count < NPOST; c++) {
    unsigned long long curw =
        (c < 64) ? __shfl(rlo, c) : __shfl(rhi, c - 64);
    unsigned long long cand = ~curw;
    while (cand != 0ull && count < NPOST) {
      int b = __builtin_ctzll(cand);
      int i = c * 64 + b;
      if (lane == 0) kept[count] = i;
      count++;
      const unsigned long long* row = mask + ((size_t)n * NPRE + i) * 94;
      unsigned long long r0 = row[lane];
      unsigned long long r1 = (64 + lane < 94) ? row[64 + lane] : 0ull;
      rlo |= r0; rhi |= r1;
      curw = (c < 64) ? __shfl(rlo, c) : __shfl(rhi, c - 64);
      cand = ~curw;
      cand &= (b == 63) ? 0ull : (~0ull << (b + 1));
    }
  }

  float* rois = out + ROIS_OFF + (size_t)n * NPOST * 4;
  float* ridx = out + RIDX_OFF + (size_t)n * NPOST;
  for (int s = lane; s < NPOST; s += 64) {
    float4 v = {0.f, 0.f, 0.f, 0.f};
    if (s < count) {
      int i = kept[s];
      v = *(const float4*)(sboxes + ((size_t)n * NPRE + i) * 4);
    }
    *(float4*)(rois + (size_t)s * 4) = v;
    ridx[s] = (float)n;
  }
}

// =====================================================================
extern "C" void kernel_launch(void* const* d_in, const int* in_sizes, int n_in,
                              void* d_out, int out_size, void* d_ws,
                              size_t ws_size, hipStream_t stream) {
  const float* feat = (const float*)d_in[0];
  const float* w1 = (const float*)d_in[1];
  const float* b1 = (const float*)d_in[2];
  const float* sw = (const float*)d_in[3];
  const float* sb = (const float*)d_in[4];
  const float* lw = (const float*)d_in[5];
  const float* lb = (const float*)d_in[6];
  const int* pimh = (const int*)d_in[7];
  const int* pimw = (const int*)d_in[8];
  float* out = (float*)d_out;
  char* ws = (char*)d_ws;

  float* wt = (float*)(ws + WT_OFF);
  _Float16* wth = (_Float16*)(ws + WTH_OFF);
  _Float16* wtl = (_Float16*)(ws + WTL_OFF);
  _Float16* xth = (_Float16*)(ws + XTH_OFF);
  _Float16* xtl = (_Float16*)(ws + XTL_OFF);
  float* w54p = (float*)(ws + W54_OFF);
  float* hbuf = (float*)(ws + H_OFF);
  float* boxes = (float*)(ws + BOXES_OFF);
  unsigned long long* keys = (unsigned long long*)(ws + KEYS_OFF);
  unsigned int* hist = (unsigned int*)(ws + HIST_OFF);
  unsigned int* prefix = (unsigned int*)(ws + PREFIX_OFF);
  unsigned int* prefix_mut = (unsigned int*)(ws + PREFIXM_OFF);
  unsigned long long* sorted = (unsigned long long*)(ws + SORTED_OFF);
  unsigned long long* skeys = (unsigned long long*)(ws + SKEYS_OFF);
  float* sboxes = (float*)(ws + SBOXES_OFF);
  unsigned long long* vmask = (unsigned long long*)(ws + VMASK_OFF);
  unsigned long long* nmask = (unsigned long long*)(ws + MASK_OFF);

  hipMemsetAsync(ws + HIST_OFF, 0, 524288, stream);
  // sentinel-fill sorted[]: unwritten slots read as key >= 0xFF800000...
  hipMemsetAsync(ws + SORTED_OFF, 0xFF, 131072, stream);

  bool big = (ws_size >= WS_NEED_MFMA);
  if (big) {
    prep16_kernel<<<288, 1024, 0, stream>>>(w1, wth, wtl, lw, sw, w54p);
    prepx_kernel<<<2048, 256, 0, stream>>>(feat, xth, xtl);
    conv1_mfma_kernel<<<dim3(128, 4), 256, 0, stream>>>(xth, xtl, wth, wtl,
                                                        b1, hbuf);
  } else {
    prep_kernel<<<288, 1024, 0, stream>>>(w1, wt, lw, sw, w54p);
    conv1_kernel<<<dim3(128, 4), 256, 0, stream>>>(feat, wt, b1, hbuf);
  }
  heads_kernel<<<128, 256, 0, stream>>>(hbuf, w54p, lb, sb, out);
  decode_kernel<<<288, 256, 0, stream>>>(out, pimh, pimw, boxes, keys, hist,
                                         out);
  scanfull_kernel<<<2, 1024, 0, stream>>>(hist, prefix, prefix_mut);
  scatter_kernel<<<288, 256, 0, stream>>>(keys, prefix_mut, sorted);
  fixup_kernel<<<56, 256, 0, stream>>>(sorted, prefix, hist, boxes, skeys,
                                       sboxes);
  nms_mask_kernel<<<dim3(94, 94, 2), 64, 0, stream>>>(sboxes, skeys, vmask,
                                                      nmask);
  nms_reduce_kernel<<<2, 1024, 0, stream>>>(nmask, vmask, sboxes, out);
}

// Round 13
// 607.018 us; speedup vs baseline: 1.0236x; 1.0236x over previous
//
#include <hip/hip_runtime.h>
#include <cmath>

#define NANCH 36864
#define NPRE 6000
#define NPOST 300

// ---- output (float) offsets ----
#define LOCS_OFF   0
#define SCORES_OFF 294912
#define ROIS_OFF   442368
#define RIDX_OFF   444768
#define ANCH_OFF   445368

// ---- workspace byte offsets ----
#define WT_OFF      0ull          // fallback: 9*512*512*4 = 9437184 fp32 wt
#define WTH_OFF     0ull          // mfma: f16 hi 9*512*512*2 = 4718592
#define WTL_OFF     4718592ull    // mfma: f16 lo (scaled 2^10)
#define PREFIX_OFF  2097152ull    // 2*65536*4 (inside dead WT region)
#define PREFIXM_OFF 2621440ull
#define SORTED_OFF  3145728ull
#define MASK_OFF    0ull          // reuse after fixup
#define H_OFF       9437184ull    // 2*512*4096*4  = 16777216
#define BOXES_OFF   26214400ull
#define W54_OFF     26214400ull
#define KEYS_OFF    27394048ull
#define HIST_OFF    27983872ull
#define SKEYS_OFF   28631168ull
#define SBOXES_OFF  28727168ull
#define VMASK_OFF   29033856ull
// MFMA-path extra regions (only if ws_size >= 46137344):
#define XTH_OFF     29360128ull   // x f16 hi: 2*64*16*64*32*2 = 8388608
#define XTL_OFF     37748736ull   // x f16 lo (scaled 2^10)
#define WS_NEED_MFMA 46137344ull

typedef _Float16 half8 __attribute__((ext_vector_type(8)));
typedef float floatx4 __attribute__((ext_vector_type(4)));

__device__ __forceinline__ void load_lds16(const float* g, float* l) {
#if __has_builtin(__builtin_amdgcn_global_load_lds)
  __builtin_amdgcn_global_load_lds(
      (const __attribute__((address_space(1))) void*)g,
      (__attribute__((address_space(3))) void*)l, 16, 0, 0);
#else
  int lane = threadIdx.x & 63;
  float4 v = *(const float4*)g;
  *(float4*)((char*)l + lane * 16) = v;
#endif
}

__device__ __forceinline__ void load_lds16g(const void* g, void* l) {
#if __has_builtin(__builtin_amdgcn_global_load_lds)
  __builtin_amdgcn_global_load_lds(
      (const __attribute__((address_space(1))) void*)g,
      (__attribute__((address_space(3))) void*)l, 16, 0, 0);
#else
  int lane = threadIdx.x & 63;
  float4 v = *(const float4*)g;
  *(float4*)((char*)l + lane * 16) = v;
#endif
}

// =====================================================================
// prep (FALLBACK path): fused weight transposes (R10/R11-verified)
// =====================================================================
__global__ __launch_bounds__(1024) void prep_kernel(
    const float* __restrict__ w, float* __restrict__ wt,
    const float* __restrict__ lw, const float* __restrict__ sw,
    float* __restrict__ w54p) {
  __shared__ float lds[9][32][33];
  if (blockIdx.x < 256) {
    int tx = threadIdx.x & 31;
    int ty = threadIdx.x >> 5;
    int ci0 = (blockIdx.x & 15) * 32;
    int co0 = (blockIdx.x >> 4) * 32;
    const float* src = w + ((size_t)(co0 + ty) * 512 + (ci0 + tx)) * 9;
#pragma unroll
    for (int k = 0; k < 9; k++) lds[k][tx][ty] = src[k];
    __syncthreads();
#pragma unroll
    for (int k = 0; k < 9; k++) {
      wt[((size_t)k * 512 + (ci0 + ty)) * 512 + co0 + tx] = lds[k][ty][tx];
    }
  } else {
    int t = (blockIdx.x - 256) * 1024 + threadIdx.x;
    int k = t >> 6, co = t & 63;
    float v = 0.f;
    if (co < 36) v = lw[(size_t)co * 512 + k];
    else if (co < 54) v = sw[(size_t)(co - 36) * 512 + k];
    w54p[t] = v;
  }
}

// =====================================================================
// prep16 (MFMA path): conv1 weights -> f16 hi/lo.
// R9 layout (kept): [9 k][4 co_tile][16 cs][4 g][128 co][8 ci] f16 —
// bank-conflict-free ds_read_b128 in conv; bit-identical h.
// =====================================================================
__global__ __launch_bounds__(1024) void prep16_kernel(
    const float* __restrict__ w, _Float16* __restrict__ wth,
    _Float16* __restrict__ wtl, const float* __restrict__ lw,
    const float* __restrict__ sw, float* __restrict__ w54p) {
  if (blockIdx.x < 256) {
    int tx = threadIdx.x & 31;              // ci within 32-block
    int ty = threadIdx.x >> 5;              // co within 32-block
    int ci0 = (blockIdx.x & 15) * 32;
    int co0 = (blockIdx.x >> 4) * 32;
    int ci = ci0 + tx, co = co0 + ty;
    const float* src = w + ((size_t)co * 512 + ci) * 9;
    int cot = co >> 7, coin = co & 127;
    int cs = ci >> 5, gg = (ci >> 3) & 3, cii = ci & 7;
    size_t obase = ((((size_t)cot) * 16 + cs) * 4 + gg) * 1024 +
                   (size_t)coin * 8 + cii;
#pragma unroll
    for (int k = 0; k < 9; k++) {
      float v = src[k];
      _Float16 h = (_Float16)v;
      _Float16 l = (_Float16)((v - (float)h) * 1024.f);
      size_t o = (size_t)k * 262144 + obase;
      wth[o] = h;
      wtl[o] = l;
    }
  } else {
    int t = (blockIdx.x - 256) * 1024 + threadIdx.x;
    int k = t >> 6, co = t & 63;
    float v = 0.f;
    if (co < 36) v = lw[(size_t)co * 512 + k];
    else if (co < 54) v = sw[(size_t)(co - 36) * 512 + k];
    w54p[t] = v;
  }
}

// =====================================================================
// prepx (MFMA path): x[n][ci][y][px] -> xt_{h,l}[n][y][cs][g][px][8ci].
// R9 layout (kept): g-major, 16B lane stride in conv LDS.
// =====================================================================
__global__ __launch_bounds__(256) void prepx_kernel(
    const float* __restrict__ x, _Float16* __restrict__ xth,
    _Float16* __restrict__ xtl) {
  __shared__ float xs[32][65];
  int b = blockIdx.x;
  int cs = b & 15, ny = b >> 4;
  int n = ny >> 6, y = ny & 63;
  int tid = threadIdx.x;
  const float* xb = x + ((size_t)n << 21) + (y << 6);
#pragma unroll
  for (int p = 0; p < 8; p++) {
    int c = p * 4 + (tid >> 6);
    xs[c][tid & 63] = xb[((size_t)(cs * 32 + c) << 12) + (tid & 63)];
  }
  __syncthreads();
  int px = tid & 63, gx = tid >> 6;        // 4 groups x 64 px
  unsigned int hw[4], lw2[4];
#pragma unroll
  for (int j = 0; j < 4; j++) {
    float v0 = xs[gx * 8 + 2 * j][px], v1 = xs[gx * 8 + 2 * j + 1][px];
    _Float16 h0 = (_Float16)v0, h1 = (_Float16)v1;
    _Float16 l0 = (_Float16)((v0 - (float)h0) * 1024.f);
    _Float16 l1 = (_Float16)((v1 - (float)h1) * 1024.f);
    hw[j] = (unsigned int)__builtin_bit_cast(unsigned short, h0) |
            ((unsigned int)__builtin_bit_cast(unsigned short, h1) << 16);
    lw2[j] = (unsigned int)__builtin_bit_cast(unsigned short, l0) |
             ((unsigned int)__builtin_bit_cast(unsigned short, l1) << 16);
  }
  size_t o = (size_t)b * 2048 + (size_t)gx * 512 + (size_t)px * 8;
  uint4 hv; hv.x = hw[0]; hv.y = hw[1]; hv.z = hw[2]; hv.w = hw[3];
  uint4 lv; lv.x = lw2[0]; lv.y = lw2[1]; lv.z = lw2[2]; lv.w = lw2[3];
  *(uint4*)(xth + o) = hv;
  *(uint4*)(xtl + o) = lv;
}

// =====================================================================
// conv1 MFMA (R10-proven, 134us, RESTORED): f16x3 split precision,
// W staged via LDS, R9 conflict-free layouts. R11/R12's direct
// global->reg W (barrier removal) was neutral-to-worse: the kernel is
// LDS-read-throughput bound (~12 waves x 8 ds_read_b128 per tap-round
// vs 360cy MFMA/SIMD), NOT barrier-bound. This decomposition's floor.
// =====================================================================
__global__ __launch_bounds__(256, 3) void conv1_mfma_kernel(
    const _Float16* __restrict__ xth, const _Float16* __restrict__ xtl,
    const _Float16* __restrict__ wth, const _Float16* __restrict__ wtl,
    const float* __restrict__ bias, float* __restrict__ hout) {
  __shared__ __align__(16) _Float16 sXh[6336];   // [3 yr][4 g][66 row][8]
  __shared__ __align__(16) _Float16 sXl[6336];
  __shared__ __align__(16) _Float16 sWh[4096];   // [4 g][128 co][8]
  __shared__ __align__(16) _Float16 sWl[4096];
  int mb = blockIdx.x;
  int n = mb >> 6, y = mb & 63;
  int co0 = blockIdx.y << 7;
  int tid = threadIdx.x;
  int wv = tid >> 6, lane = tid & 63;
  int m15 = lane & 15, g = lane >> 4;

  floatx4 accm[2][4], accl[2][4];
#pragma unroll
  for (int ct = 0; ct < 2; ct++)
#pragma unroll
    for (int pt = 0; pt < 4; pt++) {
      accm[ct][pt] = (floatx4){0.f, 0.f, 0.f, 0.f};
      accl[ct][pt] = (floatx4){0.f, 0.f, 0.f, 0.f};
    }

  // zero X LDS once: pad rows 0/65 of each g-group + invalid-yr slices
  for (int t2 = tid; t2 < 3168; t2 += 256) {
    ((unsigned int*)sXh)[t2] = 0u;
    ((unsigned int*)sXl)[t2] = 0u;
  }
  __syncthreads();

  bool yv0 = (y > 0), yv2 = (y < 63);
  int p = wv >> 1, hf = wv & 1;
  _Float16* wdst = p ? sWl : sWh;
  const _Float16* wsel = p ? wtl : wth;

  for (int cs = 0; cs < 16; cs++) {
    // ---- X DMA: 24 wave-DMAs (6/wave): (yr, part, g) x 1KB linear ----
    {
      int base = wv * 6;
#pragma unroll
      for (int i = 0; i < 6; i++) {
        int idx = base + i;                 // 0..23
        int yr = idx >> 3, rem = idx & 7;
        int part = rem >> 2, d = rem & 3;   // d = g-group
        int ys = y + yr - 1;
        if (ys >= 0 && ys < 64) {           // wave-uniform
          const _Float16* s =
              (part ? xtl : xth) +
              ((((size_t)(n * 64 + ys)) * 16 + cs) << 11) + (d << 9) +
              (lane << 3);
          _Float16* dst = (part ? sXl : sXh) + yr * 2112 + d * 528 + 8;
          load_lds16g(s, dst);
        }
      }
    }
    // W tile base for this (co-tile, cs): [4 g][128 co][8] contiguous
    size_t woff0 = (size_t)(co0 >> 7) * 65536 + (size_t)cs * 4096;
    const _Float16* wsrc0 = wsel + woff0 + (lane << 3);
#pragma unroll
    for (int tap = 0; tap < 9; tap++) {
      int ky = tap / 3;
      int kx = tap - ky * 3;
      if (ky == 0 && !yv0) continue;        // block-uniform: zero slice
      if (ky == 2 && !yv2) continue;
      // ---- W DMA: wave (p,hf) loads g-groups {2hf, 2hf+1}, 4x1KB ----
      const _Float16* ws = wsrc0 + (size_t)tap * 262144;
#pragma unroll
      for (int e = 0; e < 4; e++) {
        int gd = hf * 2 + (e >> 1), half = e & 1;
        load_lds16g(ws + gd * 1024 + half * 512,
                    wdst + gd * 1024 + half * 512);
      }
      __syncthreads();
      // ---- frags (16B lane stride: conflict-free) ----
      half8 Ah[2], Al[2], Bh[4], Bl[4];
#pragma unroll
      for (int ct = 0; ct < 2; ct++) {
        int ao = (g << 10) + (((wv << 5) + (ct << 4) + m15) << 3);
        Ah[ct] = *(const half8*)(sWh + ao);
        Al[ct] = *(const half8*)(sWl + ao);
      }
#pragma unroll
      for (int pt = 0; pt < 4; pt++) {
        int bo = ky * 2112 + g * 528 + (((pt << 4) + m15 + kx) << 3);
        Bh[pt] = *(const half8*)(sXh + bo);
        Bl[pt] = *(const half8*)(sXl + bo);
      }
#pragma unroll
      for (int ct = 0; ct < 2; ct++)
#pragma unroll
        for (int pt = 0; pt < 4; pt++) {
          accm[ct][pt] = __builtin_amdgcn_mfma_f32_16x16x32_f16(
              Ah[ct], Bh[pt], accm[ct][pt], 0, 0, 0);
          accl[ct][pt] = __builtin_amdgcn_mfma_f32_16x16x32_f16(
              Ah[ct], Bl[pt], accl[ct][pt], 0, 0, 0);
          accl[ct][pt] = __builtin_amdgcn_mfma_f32_16x16x32_f16(
              Al[ct], Bh[pt], accl[ct][pt], 0, 0, 0);
        }
      __syncthreads();
    }
  }

#pragma unroll
  for (int ct = 0; ct < 2; ct++)
#pragma unroll
    for (int pt = 0; pt < 4; pt++) {
#pragma unroll
      for (int r = 0; r < 4; r++) {
        int co = co0 + (wv << 5) + (ct << 4) + (g << 2) + r;
        float v = accm[ct][pt][r] + accl[ct][pt][r] * 0.0009765625f +
                  bias[co];
        hout[((size_t)(n * 512 + co) << 12) + (y << 6) + (pt << 4) + m15] =
            fmaxf(v, 0.f);
      }
    }
}

// =====================================================================
// conv1 v9 (FALLBACK, proven): fp32 3x3 512->512 + bias + ReLU.
// =====================================================================
__global__ __launch_bounds__(256) void conv1_kernel(
    const float* __restrict__ x, const float* __restrict__ wt,
    const float* __restrict__ bias, float* __restrict__ hout) {
  __shared__ __align__(16) float smem[10752];
  int mb = blockIdx.x;
  int n = mb >> 6, y = mb & 63;
  int co0 = blockIdx.y << 7;
  int tid = threadIdx.x;
  int team = tid >> 7;
  int tl = tid & 127;
  int cibase = team << 8;
  float* Asb = smem + team * 768;
  float* Bsb = smem + 1536 + team * 4608;
  int tx = tl & 7, ty = tl >> 3;
  int x0 = tx << 3;

  float acc[8][8];
#pragma unroll
  for (int j = 0; j < 8; j++)
#pragma unroll
    for (int i = 0; i < 8; i++) acc[j][i] = 0.f;

  const float* xb = x + ((size_t)n << 21);

  if (y == 0) {
    for (int t2 = tl; t2 < 256; t2 += 128) Asb[t2] = 0.f;
  }
  if (y == 63) {
    for (int t2 = tl; t2 < 256; t2 += 128) Asb[512 + t2] = 0.f;
  }

  int wv = tl >> 6;
  int lane = tl & 63;
  int lrow = lane >> 5;
  int lcol = (lane & 31) << 2;
  int aci = lane >> 4;
  int aoff = (lane & 15) << 2;

  for (int cc = 0; cc < 256; cc += 4) {
    int ci0 = cibase + cc;
    for (int yr = wv; yr < 3; yr += 2) {
      int ys = y + yr - 1;
      if (ys >= 0 && ys < 64) {
        const float* g =
            xb + (((size_t)(ci0 + aci)) << 12) + (ys << 6) + aoff;
        load_lds16(g, &Asb[yr << 8]);
      }
    }
    for (int i = 0; i < 9; i++) {
      int r0 = i * 4 + wv * 2;
      int row = r0 + lrow;
      int kk = row >> 2, ci = row & 3;
      const float* g = wt + (((size_t)(kk << 9)) + ci0 + ci) * 512 + co0 + lcol;
      load_lds16(g, &Bsb[r0 << 7]);
    }
    __syncthreads();
    for (int k = 0; k < 4; k++) {
#pragma unroll
      for (int ky = 0; ky < 3; ky++) {
        const float* arr = &Asb[((ky << 2) + k) << 6];
        float w10[10];
        w10[0] = (tx == 0) ? 0.f : arr[x0 - 1];
        float4 a0 = *(const float4*)&arr[x0];
        float4 a1 = *(const float4*)&arr[x0 + 4];
        w10[1] = a0.x; w10[2] = a0.y; w10[3] = a0.z; w10[4] = a0.w;
        w10[5] = a1.x; w10[6] = a1.y; w10[7] = a1.z; w10[8] = a1.w;
        w10[9] = (tx == 7) ? 0.f : arr[x0 + 8];
#pragma unroll
        for (int kx = 0; kx < 3; kx++) {
          int kk = ky * 3 + kx;
          const float* br = &Bsb[(((kk << 2) + k) << 7) + (ty << 3)];
          float4 b0 = *(const float4*)br;
          float4 b1 = *(const float4*)(br + 4);
          float bb[8] = {b0.x, b0.y, b0.z, b0.w, b1.x, b1.y, b1.z, b1.w};
#pragma unroll
          for (int j = 0; j < 8; j++)
#pragma unroll
            for (int dx = 0; dx < 8; dx++)
              acc[j][dx] = fmaf(w10[kx + dx], bb[j], acc[j][dx]);
        }
      }
    }
    __syncthreads();
  }

  if (team == 1) {
#pragma unroll
    for (int j = 0; j < 8; j++) {
      *(float4*)&smem[tl * 68 + (j << 3)] = *(float4*)&acc[j][0];
      *(float4*)&smem[tl * 68 + (j << 3) + 4] = *(float4*)&acc[j][4];
    }
  }
  __syncthreads();
  if (team == 0) {
#pragma unroll
    for (int j = 0; j < 8; j++) {
      int co = co0 + (ty << 3) + j;
      float bv = bias[co];
      float4 p0 = *(float4*)&smem[tl * 68 + (j << 3)];
      float4 p1 = *(float4*)&smem[tl * 68 + (j << 3) + 4];
      float4 v0, v1;
      v0.x = fmaxf((acc[j][0] + p0.x) + bv, 0.f);
      v0.y = fmaxf((acc[j][1] + p0.y) + bv, 0.f);
      v0.z = fmaxf((acc[j][2] + p0.z) + bv, 0.f);
      v0.w = fmaxf((acc[j][3] + p0.w) + bv, 0.f);
      v1.x = fmaxf((acc[j][4] + p1.x) + bv, 0.f);
      v1.y = fmaxf((acc[j][5] + p1.y) + bv, 0.f);
      v1.z = fmaxf((acc[j][6] + p1.z) + bv, 0.f);
      v1.w = fmaxf((acc[j][7] + p1.w) + bv, 0.f);
      float* o = &hout[(((size_t)(n * 512 + co)) << 12) + (y << 6) + x0];
      *(float4*)o = v0;
      *(float4*)(o + 4) = v1;
    }
  }
}

// =====================================================================
// heads v2 (proven): tiled GEMM M=64p x N=54 x K=512.
// =====================================================================
__global__ __launch_bounds__(256) void heads_kernel(
    const float* __restrict__ h, const float* __restrict__ w54p,
    const float* __restrict__ loc_b, const float* __restrict__ score_b,
    float* __restrict__ out) {
  __shared__ __align__(16) float hs[32 * 64];
  __shared__ __align__(16) float wsd[32 * 64];
  __shared__ float sacc[64 * 65];
  int n = blockIdx.x >> 6;
  int p0 = (blockIdx.x & 63) << 6;
  int tid = threadIdx.x;
  int txp = tid & 63;
  int tw = tid >> 6;
  float acc[16];
#pragma unroll
  for (int j = 0; j < 16; j++) acc[j] = 0.f;
  const float* hb = h + ((size_t)n * 512) * 4096 + p0;
  for (int k0 = 0; k0 < 512; k0 += 32) {
    for (int t = tid; t < 512; t += 256) {
      int r = t >> 4, l = (t & 15) << 2;
      *(float4*)&hs[(r << 6) + l] =
          *(const float4*)&hb[(((size_t)(k0 + r)) << 12) + l];
      *(float4*)&wsd[(r << 6) + l] =
          *(const float4*)&w54p[((k0 + r) << 6) + l];
    }
    __syncthreads();
    for (int k = 0; k < 32; k++) {
      float hv = hs[(k << 6) + txp];
      const float* wr = &wsd[(k << 6) + (tw << 4)];
#pragma unroll
      for (int u = 0; u < 4; u++) {
        float4 wv = *(const float4*)(wr + (u << 2));
        acc[u * 4 + 0] = fmaf(hv, wv.x, acc[u * 4 + 0]);
        acc[u * 4 + 1] = fmaf(hv, wv.y, acc[u * 4 + 1]);
        acc[u * 4 + 2] = fmaf(hv, wv.z, acc[u * 4 + 2]);
        acc[u * 4 + 3] = fmaf(hv, wv.w, acc[u * 4 + 3]);
      }
    }
    __syncthreads();
  }
#pragma unroll
  for (int j = 0; j < 16; j++) sacc[(tw * 16 + j) * 65 + txp] = acc[j];
  __syncthreads();
  for (int t = tid; t < 64 * 54; t += 256) {
    int p = t / 54, c = t - p * 54;
    float v = sacc[c * 65 + p];
    int gp = (n << 12) + p0 + p;
    if (c < 36) out[LOCS_OFF + (size_t)gp * 36 + c] = v + loc_b[c];
    else out[SCORES_OFF + (size_t)gp * 18 + (c - 36)] = v + score_b[c - 36];
  }
}

// =====================================================================
// Decode (anchors fused + hist fused; valid-only hist atomics, R5)
// =====================================================================
__global__ void decode_kernel(const float* __restrict__ out_ro,
                              const int* __restrict__ pimh,
                              const int* __restrict__ pimw,
                              float* __restrict__ boxes,
                              unsigned long long* __restrict__ keys,
                              unsigned int* __restrict__ hist,
                              float* __restrict__ out) {
  int t = blockIdx.x * 256 + threadIdx.x;
  int n = t / NANCH, k = t - n * NANCH;
  float imh = (float)pimh[0], imw = (float)pimw[0];

  int a = k % 9, pos = k / 9;
  int jj = pos & 63, ii = pos >> 6;
  int ridx = a / 3, sidx = a % 3;
  double r = (ridx == 0) ? 0.5 : ((ridx == 1) ? 1.0 : 2.0);
  double s = (sidx == 0) ? 8.0 : ((sidx == 1) ? 16.0 : 32.0);
  double ahh = 16.0 * s * sqrt(r);
  double aww = 16.0 * s * sqrt(1.0 / r);
  float b0 = (float)(8.0 - ahh / 2.0), b1 = (float)(8.0 - aww / 2.0);
  float b2 = (float)(8.0 + ahh / 2.0), b3 = (float)(8.0 + aww / 2.0);
  float sy = (float)(ii * 16), sx = (float)(jj * 16);
  float a0 = sy + b0, a1 = sx + b1, a2 = sy + b2, a3 = sx + b3;
  if (n == 0) {
    float* o = out + ANCH_OFF + (size_t)k * 4;
    o[0] = a0; o[1] = a1; o[2] = a2; o[3] = a3;
  }

  const float* loc = out_ro + LOCS_OFF + (size_t)t * 4;
  const float* sc = out_ro + SCORES_OFF + (size_t)t * 2;
  float ah = __fsub_rn(a2, a0), aw = __fsub_rn(a3, a1);
  float acy = __fadd_rn(a0, 0.5f * ah), acx = __fadd_rn(a1, 0.5f * aw);
  float dy = loc[0], dx = loc[1], dh = loc[2], dw = loc[3];
  float cy = __fadd_rn(__fmul_rn(dy, ah), acy);
  float cx = __fadd_rn(__fmul_rn(dx, aw), acx);
  float hh = __fmul_rn(expf(dh), ah);
  float ww = __fmul_rn(expf(dw), aw);
  float y1 = __fsub_rn(cy, 0.5f * hh), x1 = __fsub_rn(cx, 0.5f * ww);
  float y2 = __fadd_rn(cy, 0.5f * hh), x2 = __fadd_rn(cx, 0.5f * ww);
  y1 = fminf(fmaxf(y1, 0.f), imh); x1 = fminf(fmaxf(x1, 0.f), imw);
  y2 = fminf(fmaxf(y2, 0.f), imh); x2 = fminf(fmaxf(x2, 0.f), imw);
  bool valid = (__fsub_rn(y2, y1) >= 16.f) && (__fsub_rn(x2, x1) >= 16.f);
  float s0 = sc[0], s1 = sc[1];
  float m = fmaxf(s0, s1);
  float e0 = expf(__fsub_rn(s0, m)), e1 = expf(__fsub_rn(s1, m));
  float fg = __fdiv_rn(e1, __fadd_rn(e0, e1));
  float score = valid ? fg : -INFINITY;
  unsigned int u = __float_as_uint(score);
  unsigned int ord = (u & 0x80000000u) ? ~u : (u | 0x80000000u);
  unsigned long long key =
      ((unsigned long long)(~ord) << 16) | (unsigned long long)(k & 0xFFFF);
  float4 b4; b4.x = y1; b4.y = x1; b4.z = y2; b4.w = x2;
  *(float4*)(boxes + (size_t)t * 4) = b4;
  keys[t] = key;
  if (valid)
    atomicAdd(&hist[((size_t)n << 16) + (unsigned int)(key >> 32)], 1u);
}

// =====================================================================
// Full exclusive prefix over 65536 buckets (per batch), uint4-vectorized
// =====================================================================
__global__ __launch_bounds__(1024) void scanfull_kernel(
    const unsigned int* __restrict__ hist, unsigned int* __restrict__ prefix,
    unsigned int* __restrict__ prefix_mut) {
  int n = blockIdx.x;
  const uint4* h4 = (const uint4*)(hist + ((size_t)n << 16));
  uint4* pf4 = (uint4*)(prefix + ((size_t)n << 16));
  uint4* pm4 = (uint4*)(prefix_mut + ((size_t)n << 16));
  __shared__ unsigned int ps[1024];
  int tid = threadIdx.x;
  int base4 = tid << 4;
  uint4 vals[16];
  unsigned int s = 0;
#pragma unroll
  for (int i = 0; i < 16; i++) {
    vals[i] = h4[base4 + i];
    s += vals[i].x + vals[i].y + vals[i].z + vals[i].w;
  }
  ps[tid] = s;
  __syncthreads();
  for (int off = 1; off < 1024; off <<= 1) {
    unsigned int v = ps[tid];
    unsigned int add = (tid >= off) ? ps[tid - off] : 0u;
    __syncthreads();
    ps[tid] = v + add;
    __syncthreads();
  }
  unsigned int run = ps[tid] - s;
#pragma unroll
  for (int i = 0; i < 16; i++) {
    uint4 hv = vals[i];
    uint4 pv;
    pv.x = run; run += hv.x;
    pv.y = run; run += hv.y;
    pv.z = run; run += hv.z;
    pv.w = run; run += hv.w;
    pf4[base4 + i] = pv;
    pm4[base4 + i] = pv;
  }
}

// =====================================================================
// Scatter into bucket-sorted order (skip invalid keys, R5)
// =====================================================================
__global__ void scatter_kernel(const unsigned long long* __restrict__ keys,
                               unsigned int* __restrict__ prefix_mut,
                               unsigned long long* __restrict__ sorted) {
  int t = blockIdx.x * 256 + threadIdx.x;
  int n = t / NANCH;
  unsigned long long key = keys[t];
  unsigned int b = (unsigned int)(key >> 32);
  if (b >= 0xFF80u) return;          // invalid (-inf) keys: never scattered
  unsigned int pos = atomicAdd(&prefix_mut[((size_t)n << 16) + b], 1u);
  if (pos < 8192) sorted[((size_t)n << 13) + pos] = key;
}

// =====================================================================
// Fixup: exact rank within bucket -> final sorted top-6000 + boxes
// =====================================================================
__global__ void fixup_kernel(const unsigned long long* __restrict__ sorted,
                             const unsigned int* __restrict__ prefix,
                             const unsigned int* __restrict__ hist,
                             const float* __restrict__ boxes,
                             unsigned long long* __restrict__ skeys,
                             float* __restrict__ sboxes) {
  int t = blockIdx.x * 256 + threadIdx.x;
  int n = t / 7168;
  int s = t - n * 7168;
  const unsigned long long* srt = sorted + ((size_t)n << 13);
  unsigned long long key = srt[s];
  unsigned int hi = (unsigned int)(key >> 16);
  if (hi >= 0xFF800000u) {
    if (s < NPRE) skeys[(size_t)n * NPRE + s] = key;
    return;
  }
  unsigned int b = (unsigned int)(key >> 32);
  unsigned int st = prefix[((size_t)n << 16) + b];
  if (st >= (unsigned)NPRE) return;
  unsigned int cnt = hist[((size_t)n << 16) + b];
  unsigned int r = 0;
  if (cnt > 1) {
    for (unsigned int j = 0; j < cnt; j++) r += (srt[st + j] < key) ? 1u : 0u;
  }
  unsigned int pos = st + r;
  if (pos < (unsigned)NPRE) {
    skeys[(size_t)n * NPRE + pos] = key;
    int k = (int)(key & 0xFFFFull);
    float4 bx = *(const float4*)(boxes + (((size_t)n * NANCH) + k) * 4);
    *(float4*)(sboxes + ((size_t)n * NPRE + pos) * 4) = bx;
  }
}

// =====================================================================
// NMS phase A: upper-triangle pairwise suppression bitmask (R3-proven)
// =====================================================================
__global__ __launch_bounds__(64) void nms_mask_kernel(
    const float* __restrict__ sboxes,
    const unsigned long long* __restrict__ skeys,
    unsigned long long* __restrict__ vmask,
    unsigned long long* __restrict__ mask) {
  int n = blockIdx.z;
  int ib = blockIdx.x, jb = blockIdx.y;
  if (jb < ib) return;
  int lane = threadIdx.x;
  __shared__ __align__(16) float jbox[64][4];
  int j = jb * 64 + lane;
  float4 bj4 = (j < NPRE)
                   ? *(const float4*)(sboxes + ((size_t)n * NPRE + j) * 4)
                   : float4{0.f, 0.f, 0.f, 0.f};
  *(float4*)jbox[lane] = bj4;
  __syncthreads();
  if (jb == ib) {
    int idx = ib * 64 + lane;
    bool ok = false;
    if (idx < NPRE) {
      unsigned int khi = (unsigned int)(skeys[(size_t)n * NPRE + idx] >> 16);
      ok = khi < 0xFF800000u;
    }
    unsigned long long m = __ballot(ok);
    if (lane == 0) vmask[(size_t)n * 94 + ib] = m;
  }
  int i = ib * 64 + lane;
  if (i >= NPRE) return;
  float4 bi = *(const float4*)(sboxes + ((size_t)n * NPRE + i) * 4);
  float ay1 = bi.x, ax1 = bi.y, ay2 = bi.z, ax2 = bi.w;
  float areaA = __fmul_rn(__fsub_rn(ay2, ay1), __fsub_rn(ax2, ax1));
  unsigned long long bits = 0ull;
#pragma unroll 8
  for (int l = 0; l < 64; l++) {
    float4 bj = *(const float4*)jbox[l];
    float ty1 = fmaxf(ay1, bj.x), tx1 = fmaxf(ax1, bj.y);
    float ty2 = fminf(ay2, bj.z), tx2 = fminf(ax2, bj.w);
    float wh0 = fmaxf(__fsub_rn(ty2, ty1), 0.f);
    float wh1 = fmaxf(__fsub_rn(tx2, tx1), 0.f);
    float inter = __fmul_rn(wh0, wh1);
    float areaB = __fmul_rn(__fsub_rn(bj.z, bj.x), __fsub_rn(bj.w, bj.y));
    float den = __fadd_rn(__fsub_rn(__fadd_rn(areaA, areaB), inter), 1e-9f);
    float iou = __fdiv_rn(inter, den);
    if (iou > 0.7f) bits |= (1ull << l);
  }
  mask[((size_t)n * NPRE + i) * 94 + jb] = bits;
}

// =====================================================================
// NMS phase B v6: CONCURRENT warm + serial greedy loop.
// R8 put the warm (one CU pulling 1.5MB from HBM, ~20-25us) serially
// BEFORE the loop. Now wave 0 starts the greedy loop immediately;
// waves 1-15 warm rows 0..4095 (3.1MB, L2-fits) in parallel. Read-only
// race, no ordering needed, kept[]/output untouched by warmers ->
// byte-identical result. Early links cold, later links L2-hit.
// (R9 lesson kept: no load-consuming state inside the serial loop.)
// =====================================================================
#define WARM_ROWS 4096

__global__ __launch_bounds__(1024) void nms_reduce_kernel(
    const unsigned long long* __restrict__ mask,
    const unsigned long long* __restrict__ vmask,
    const float* __restrict__ sboxes, float* __restrict__ out) {
  int n = blockIdx.x;
  __shared__ int kept[NPOST];

  if (threadIdx.x >= 64) {
    // ---- concurrent L2 warm (waves 1..15): read-only, no barrier ----
    const ulonglong2* m2 =
        (const ulonglong2*)(mask + (size_t)n * NPRE * 94);
    unsigned long long accw = 0;
    const int total = WARM_ROWS * 94 / 2;    // 192512 x 16B = 3.08 MB
    for (int i = threadIdx.x - 64; i < total; i += 960) {
      ulonglong2 v = m2[i];
      accw ^= v.x ^ v.y;
    }
    asm volatile("" :: "v"(accw));           // keep loads live (rule #17)
    return;
  }

  int lane = threadIdx.x;

  unsigned long long rlo = ~vmask[(size_t)n * 94 + lane];
  unsigned long long rhi = (64 + lane < 94) ? ~vmask[(size_t)n * 94 + 64 + lane]
                                            : ~0ull;
  int count = 0;
  for (int c = 0; c < 94 && count < NPOST; c++) {
    unsigned long long curw =
        (c < 64) ? __shfl(rlo, c) : __shfl(rhi, c - 64);
    unsigned long long cand = ~curw;
    while (cand != 0ull && count < NPOST) {
      int b = __builtin_ctzll(cand);
      int i = c * 64 + b;
      if (lane == 0) kept[count] = i;
      count++;
      const unsigned long long* row = mask + ((size_t)n * NPRE + i) * 94;
      unsigned long long r0 = row[lane];
      unsigned long long r1 = (64 + lane < 94) ? row[64 + lane] : 0ull;
      rlo |= r0; rhi |= r1;
      curw = (c < 64) ? __shfl(rlo, c) : __shfl(rhi, c - 64);
      cand = ~curw;
      cand &= (b == 63) ? 0ull : (~0ull << (b + 1));
    }
  }

  float* rois = out + ROIS_OFF + (size_t)n * NPOST * 4;
  float* ridx = out + RIDX_OFF + (size_t)n * NPOST;
  for (int s = lane; s < NPOST; s += 64) {
    float4 v = {0.f, 0.f, 0.f, 0.f};
    if (s < count) {
      int i = kept[s];
      v = *(const float4*)(sboxes + ((size_t)n * NPRE + i) * 4);
    }
    *(float4*)(rois + (size_t)s * 4) = v;
    ridx[s] = (float)n;
  }
}

// =====================================================================
extern "C" void kernel_launch(void* const* d_in, const int* in_sizes, int n_in,
                              void* d_out, int out_size, void* d_ws,
                              size_t ws_size, hipStream_t stream) {
  const float* feat = (const float*)d_in[0];
  const float* w1 = (const float*)d_in[1];
  const float* b1 = (const float*)d_in[2];
  const float* sw = (const float*)d_in[3];
  const float* sb = (const float*)d_in[4];
  const float* lw = (const float*)d_in[5];
  const float* lb = (const float*)d_in[6];
  const int* pimh = (const int*)d_in[7];
  const int* pimw = (const int*)d_in[8];
  float* out = (float*)d_out;
  char* ws = (char*)d_ws;

  float* wt = (float*)(ws + WT_OFF);
  _Float16* wth = (_Float16*)(ws + WTH_OFF);
  _Float16* wtl = (_Float16*)(ws + WTL_OFF);
  _Float16* xth = (_Float16*)(ws + XTH_OFF);
  _Float16* xtl = (_Float16*)(ws + XTL_OFF);
  float* w54p = (float*)(ws + W54_OFF);
  float* hbuf = (float*)(ws + H_OFF);
  float* boxes = (float*)(ws + BOXES_OFF);
  unsigned long long* keys = (unsigned long long*)(ws + KEYS_OFF);
  unsigned int* hist = (unsigned int*)(ws + HIST_OFF);
  unsigned int* prefix = (unsigned int*)(ws + PREFIX_OFF);
  unsigned int* prefix_mut = (unsigned int*)(ws + PREFIXM_OFF);
  unsigned long long* sorted = (unsigned long long*)(ws + SORTED_OFF);
  unsigned long long* skeys = (unsigned long long*)(ws + SKEYS_OFF);
  float* sboxes = (float*)(ws + SBOXES_OFF);
  unsigned long long* vmask = (unsigned long long*)(ws + VMASK_OFF);
  unsigned long long* nmask = (unsigned long long*)(ws + MASK_OFF);

  hipMemsetAsync(ws + HIST_OFF, 0, 524288, stream);
  // sentinel-fill sorted[]: unwritten slots read as key >= 0xFF800000...
  hipMemsetAsync(ws + SORTED_OFF, 0xFF, 131072, stream);

  bool big = (ws_size >= WS_NEED_MFMA);
  if (big) {
    prep16_kernel<<<288, 1024, 0, stream>>>(w1, wth, wtl, lw, sw, w54p);
    prepx_kernel<<<2048, 256, 0, stream>>>(feat, xth, xtl);
    conv1_mfma_kernel<<<dim3(128, 4), 256, 0, stream>>>(xth, xtl, wth, wtl,
                                                        b1, hbuf);
  } else {
    prep_kernel<<<288, 1024, 0, stream>>>(w1, wt, lw, sw, w54p);
    conv1_kernel<<<dim3(128, 4), 256, 0, stream>>>(feat, wt, b1, hbuf);
  }
  heads_kernel<<<128, 256, 0, stream>>>(hbuf, w54p, lb, sb, out);
  decode_kernel<<<288, 256, 0, stream>>>(out, pimh, pimw, boxes, keys, hist,
                                         out);
  scanfull_kernel<<<2, 1024, 0, stream>>>(hist, prefix, prefix_mut);
  scatter_kernel<<<288, 256, 0, stream>>>(keys, prefix_mut, sorted);
  fixup_kernel<<<56, 256, 0, stream>>>(sorted, prefix, hist, boxes, skeys,
                                       sboxes);
  nms_mask_kernel<<<dim3(94, 94, 2), 64, 0, stream>>>(sboxes, skeys, vmask,
                                                      nmask);
  nms_reduce_kernel<<<2, 1024, 0, stream>>>(nmask, vmask, sboxes, out);
}

// Round 14
// 606.179 us; speedup vs baseline: 1.0250x; 1.0014x over previous
//
#include <hip/hip_runtime.h>
#include <cmath>

#define NANCH 36864
#define NPRE 6000
#define NPOST 300

// ---- output (float) offsets ----
#define LOCS_OFF   0
#define SCORES_OFF 294912
#define ROIS_OFF   442368
#define RIDX_OFF   444768
#define ANCH_OFF   445368

// ---- workspace byte offsets ----
#define WT_OFF      0ull          // fallback: 9*512*512*4 = 9437184 fp32 wt
#define WTH_OFF     0ull          // mfma: f16 hi 9*512*512*2 = 4718592
#define WTL_OFF     4718592ull    // mfma: f16 lo (scaled 2^10)
#define PREFIX_OFF  2097152ull    // 2*65536*4 (inside dead WT region)
#define PREFIXM_OFF 2621440ull
#define SORTED_OFF  3145728ull
#define MASK_OFF    0ull          // reuse after fixup
#define H_OFF       9437184ull    // 2*512*4096*4  = 16777216
#define BOXES_OFF   26214400ull
#define W54_OFF     26214400ull
#define KEYS_OFF    27394048ull
#define HIST_OFF    27983872ull
#define SKEYS_OFF   28631168ull
#define SBOXES_OFF  28727168ull
#define VMASK_OFF   29033856ull
// MFMA-path extra regions (only if ws_size >= 46137344):
#define XTH_OFF     29360128ull   // x f16 hi: 2*64*16*64*32*2 = 8388608
#define XTL_OFF     37748736ull   // x f16 lo (scaled 2^10)
#define WS_NEED_MFMA 46137344ull

typedef _Float16 half8 __attribute__((ext_vector_type(8)));
typedef float floatx4 __attribute__((ext_vector_type(4)));

__device__ __forceinline__ void load_lds16(const float* g, float* l) {
#if __has_builtin(__builtin_amdgcn_global_load_lds)
  __builtin_amdgcn_global_load_lds(
      (const __attribute__((address_space(1))) void*)g,
      (__attribute__((address_space(3))) void*)l, 16, 0, 0);
#else
  int lane = threadIdx.x & 63;
  float4 v = *(const float4*)g;
  *(float4*)((char*)l + lane * 16) = v;
#endif
}

__device__ __forceinline__ void load_lds16g(const void* g, void* l) {
#if __has_builtin(__builtin_amdgcn_global_load_lds)
  __builtin_amdgcn_global_load_lds(
      (const __attribute__((address_space(1))) void*)g,
      (__attribute__((address_space(3))) void*)l, 16, 0, 0);
#else
  int lane = threadIdx.x & 63;
  float4 v = *(const float4*)g;
  *(float4*)((char*)l + lane * 16) = v;
#endif
}

// =====================================================================
// prep (FALLBACK path): fused weight transposes (R10/R11-verified)
// =====================================================================
__global__ __launch_bounds__(1024) void prep_kernel(
    const float* __restrict__ w, float* __restrict__ wt,
    const float* __restrict__ lw, const float* __restrict__ sw,
    float* __restrict__ w54p) {
  __shared__ float lds[9][32][33];
  if (blockIdx.x < 256) {
    int tx = threadIdx.x & 31;
    int ty = threadIdx.x >> 5;
    int ci0 = (blockIdx.x & 15) * 32;
    int co0 = (blockIdx.x >> 4) * 32;
    const float* src = w + ((size_t)(co0 + ty) * 512 + (ci0 + tx)) * 9;
#pragma unroll
    for (int k = 0; k < 9; k++) lds[k][tx][ty] = src[k];
    __syncthreads();
#pragma unroll
    for (int k = 0; k < 9; k++) {
      wt[((size_t)k * 512 + (ci0 + ty)) * 512 + co0 + tx] = lds[k][ty][tx];
    }
  } else {
    int t = (blockIdx.x - 256) * 1024 + threadIdx.x;
    int k = t >> 6, co = t & 63;
    float v = 0.f;
    if (co < 36) v = lw[(size_t)co * 512 + k];
    else if (co < 54) v = sw[(size_t)(co - 36) * 512 + k];
    w54p[t] = v;
  }
}

// =====================================================================
// prepall (MFMA path, R14): prep16 + prepx MERGED into one launch —
// they are data-independent but ran serially. Blocks 0..511 run FOUR
// prepx tiles each (4 x 256-thread sub-blocks; the shared
// __syncthreads is strictly stronger than the per-tile barrier).
// Blocks 512..799 run the prep16 body verbatim. All output addresses
// and values identical to R13 -> bit-identical pipeline.
//   prep16 layout: [9 k][4 co_tile][16 cs][4 g][128 co][8 ci] f16
//   prepx  layout: [n][y][cs][g][px][8ci] f16 (hi + lo*2^10)
// =====================================================================
__global__ __launch_bounds__(1024) void prepall_kernel(
    const float* __restrict__ w, _Float16* __restrict__ wth,
    _Float16* __restrict__ wtl, const float* __restrict__ lw,
    const float* __restrict__ sw, float* __restrict__ w54p,
    const float* __restrict__ x, _Float16* __restrict__ xth,
    _Float16* __restrict__ xtl) {
  __shared__ float xs[4][32][65];
  if (blockIdx.x < 512) {
    // ---- prepx: 4 tiles per block, one per 256-thread sub-block ----
    int sub = threadIdx.x >> 8;
    int tid = threadIdx.x & 255;
    int b = blockIdx.x * 4 + sub;          // 0..2047
    int cs = b & 15, ny = b >> 4;
    int n = ny >> 6, y = ny & 63;
    const float* xb = x + ((size_t)n << 21) + (y << 6);
#pragma unroll
    for (int p = 0; p < 8; p++) {
      int c = p * 4 + (tid >> 6);
      xs[sub][c][tid & 63] = xb[((size_t)(cs * 32 + c) << 12) + (tid & 63)];
    }
    __syncthreads();
    int px = tid & 63, gx = tid >> 6;      // 4 groups x 64 px
    unsigned int hw[4], lw2[4];
#pragma unroll
    for (int j = 0; j < 4; j++) {
      float v0 = xs[sub][gx * 8 + 2 * j][px];
      float v1 = xs[sub][gx * 8 + 2 * j + 1][px];
      _Float16 h0 = (_Float16)v0, h1 = (_Float16)v1;
      _Float16 l0 = (_Float16)((v0 - (float)h0) * 1024.f);
      _Float16 l1 = (_Float16)((v1 - (float)h1) * 1024.f);
      hw[j] = (unsigned int)__builtin_bit_cast(unsigned short, h0) |
              ((unsigned int)__builtin_bit_cast(unsigned short, h1) << 16);
      lw2[j] = (unsigned int)__builtin_bit_cast(unsigned short, l0) |
               ((unsigned int)__builtin_bit_cast(unsigned short, l1) << 16);
    }
    size_t o = (size_t)b * 2048 + (size_t)gx * 512 + (size_t)px * 8;
    uint4 hv; hv.x = hw[0]; hv.y = hw[1]; hv.z = hw[2]; hv.w = hw[3];
    uint4 lv; lv.x = lw2[0]; lv.y = lw2[1]; lv.z = lw2[2]; lv.w = lw2[3];
    *(uint4*)(xth + o) = hv;
    *(uint4*)(xtl + o) = lv;
  } else if (blockIdx.x < 768) {
    // ---- prep16 weight part (old blocks 0..255) ----
    int bx = blockIdx.x - 512;
    int tx = threadIdx.x & 31;             // ci within 32-block
    int ty = threadIdx.x >> 5;             // co within 32-block
    int ci0 = (bx & 15) * 32;
    int co0 = (bx >> 4) * 32;
    int ci = ci0 + tx, co = co0 + ty;
    const float* src = w + ((size_t)co * 512 + ci) * 9;
    int cot = co >> 7, coin = co & 127;
    int cs = ci >> 5, gg = (ci >> 3) & 3, cii = ci & 7;
    size_t obase = ((((size_t)cot) * 16 + cs) * 4 + gg) * 1024 +
                   (size_t)coin * 8 + cii;
#pragma unroll
    for (int k = 0; k < 9; k++) {
      float v = src[k];
      _Float16 h = (_Float16)v;
      _Float16 l = (_Float16)((v - (float)h) * 1024.f);
      size_t o = (size_t)k * 262144 + obase;
      wth[o] = h;
      wtl[o] = l;
    }
  } else {
    // ---- prep16 w54p tail (old blocks 256..287) ----
    int t = (blockIdx.x - 768) * 1024 + threadIdx.x;   // < 32768
    int k = t >> 6, co = t & 63;
    float v = 0.f;
    if (co < 36) v = lw[(size_t)co * 512 + k];
    else if (co < 54) v = sw[(size_t)(co - 36) * 512 + k];
    w54p[t] = v;
  }
}

// =====================================================================
// conv1 MFMA (R10-proven, ~135us): f16x3 split precision, W staged via
// LDS, R9 conflict-free layouts. AT ITS LDS-BW ROOFLINE for this tile
// config: 12 waves x 12 ds_read_b128/tap = 1152 clk LDS demand/CU at
// 128B/clk peak vs 360 clk MFMA -> MfmaUtil cap ~31-36% (measured 36).
// =====================================================================
__global__ __launch_bounds__(256, 3) void conv1_mfma_kernel(
    const _Float16* __restrict__ xth, const _Float16* __restrict__ xtl,
    const _Float16* __restrict__ wth, const _Float16* __restrict__ wtl,
    const float* __restrict__ bias, float* __restrict__ hout) {
  __shared__ __align__(16) _Float16 sXh[6336];   // [3 yr][4 g][66 row][8]
  __shared__ __align__(16) _Float16 sXl[6336];
  __shared__ __align__(16) _Float16 sWh[4096];   // [4 g][128 co][8]
  __shared__ __align__(16) _Float16 sWl[4096];
  int mb = blockIdx.x;
  int n = mb >> 6, y = mb & 63;
  int co0 = blockIdx.y << 7;
  int tid = threadIdx.x;
  int wv = tid >> 6, lane = tid & 63;
  int m15 = lane & 15, g = lane >> 4;

  floatx4 accm[2][4], accl[2][4];
#pragma unroll
  for (int ct = 0; ct < 2; ct++)
#pragma unroll
    for (int pt = 0; pt < 4; pt++) {
      accm[ct][pt] = (floatx4){0.f, 0.f, 0.f, 0.f};
      accl[ct][pt] = (floatx4){0.f, 0.f, 0.f, 0.f};
    }

  // zero X LDS once: pad rows 0/65 of each g-group + invalid-yr slices
  for (int t2 = tid; t2 < 3168; t2 += 256) {
    ((unsigned int*)sXh)[t2] = 0u;
    ((unsigned int*)sXl)[t2] = 0u;
  }
  __syncthreads();

  bool yv0 = (y > 0), yv2 = (y < 63);
  int p = wv >> 1, hf = wv & 1;
  _Float16* wdst = p ? sWl : sWh;
  const _Float16* wsel = p ? wtl : wth;

  for (int cs = 0; cs < 16; cs++) {
    // ---- X DMA: 24 wave-DMAs (6/wave): (yr, part, g) x 1KB linear ----
    {
      int base = wv * 6;
#pragma unroll
      for (int i = 0; i < 6; i++) {
        int idx = base + i;                 // 0..23
        int yr = idx >> 3, rem = idx & 7;
        int part = rem >> 2, d = rem & 3;   // d = g-group
        int ys = y + yr - 1;
        if (ys >= 0 && ys < 64) {           // wave-uniform
          const _Float16* s =
              (part ? xtl : xth) +
              ((((size_t)(n * 64 + ys)) * 16 + cs) << 11) + (d << 9) +
              (lane << 3);
          _Float16* dst = (part ? sXl : sXh) + yr * 2112 + d * 528 + 8;
          load_lds16g(s, dst);
        }
      }
    }
    // W tile base for this (co-tile, cs): [4 g][128 co][8] contiguous
    size_t woff0 = (size_t)(co0 >> 7) * 65536 + (size_t)cs * 4096;
    const _Float16* wsrc0 = wsel + woff0 + (lane << 3);
#pragma unroll
    for (int tap = 0; tap < 9; tap++) {
      int ky = tap / 3;
      int kx = tap - ky * 3;
      if (ky == 0 && !yv0) continue;        // block-uniform: zero slice
      if (ky == 2 && !yv2) continue;
      // ---- W DMA: wave (p,hf) loads g-groups {2hf, 2hf+1}, 4x1KB ----
      const _Float16* ws = wsrc0 + (size_t)tap * 262144;
#pragma unroll
      for (int e = 0; e < 4; e++) {
        int gd = hf * 2 + (e >> 1), half = e & 1;
        load_lds16g(ws + gd * 1024 + half * 512,
                    wdst + gd * 1024 + half * 512);
      }
      __syncthreads();
      // ---- frags (16B lane stride: conflict-free) ----
      half8 Ah[2], Al[2], Bh[4], Bl[4];
#pragma unroll
      for (int ct = 0; ct < 2; ct++) {
        int ao = (g << 10) + (((wv << 5) + (ct << 4) + m15) << 3);
        Ah[ct] = *(const half8*)(sWh + ao);
        Al[ct] = *(const half8*)(sWl + ao);
      }
#pragma unroll
      for (int pt = 0; pt < 4; pt++) {
        int bo = ky * 2112 + g * 528 + (((pt << 4) + m15 + kx) << 3);
        Bh[pt] = *(const half8*)(sXh + bo);
        Bl[pt] = *(const half8*)(sXl + bo);
      }
#pragma unroll
      for (int ct = 0; ct < 2; ct++)
#pragma unroll
        for (int pt = 0; pt < 4; pt++) {
          accm[ct][pt] = __builtin_amdgcn_mfma_f32_16x16x32_f16(
              Ah[ct], Bh[pt], accm[ct][pt], 0, 0, 0);
          accl[ct][pt] = __builtin_amdgcn_mfma_f32_16x16x32_f16(
              Ah[ct], Bl[pt], accl[ct][pt], 0, 0, 0);
          accl[ct][pt] = __builtin_amdgcn_mfma_f32_16x16x32_f16(
              Al[ct], Bh[pt], accl[ct][pt], 0, 0, 0);
        }
      __syncthreads();
    }
  }

#pragma unroll
  for (int ct = 0; ct < 2; ct++)
#pragma unroll
    for (int pt = 0; pt < 4; pt++) {
#pragma unroll
      for (int r = 0; r < 4; r++) {
        int co = co0 + (wv << 5) + (ct << 4) + (g << 2) + r;
        float v = accm[ct][pt][r] + accl[ct][pt][r] * 0.0009765625f +
                  bias[co];
        hout[((size_t)(n * 512 + co) << 12) + (y << 6) + (pt << 4) + m15] =
            fmaxf(v, 0.f);
      }
    }
}

// =====================================================================
// conv1 v9 (FALLBACK, proven): fp32 3x3 512->512 + bias + ReLU.
// =====================================================================
__global__ __launch_bounds__(256) void conv1_kernel(
    const float* __restrict__ x, const float* __restrict__ wt,
    const float* __restrict__ bias, float* __restrict__ hout) {
  __shared__ __align__(16) float smem[10752];
  int mb = blockIdx.x;
  int n = mb >> 6, y = mb & 63;
  int co0 = blockIdx.y << 7;
  int tid = threadIdx.x;
  int team = tid >> 7;
  int tl = tid & 127;
  int cibase = team << 8;
  float* Asb = smem + team * 768;
  float* Bsb = smem + 1536 + team * 4608;
  int tx = tl & 7, ty = tl >> 3;
  int x0 = tx << 3;

  float acc[8][8];
#pragma unroll
  for (int j = 0; j < 8; j++)
#pragma unroll
    for (int i = 0; i < 8; i++) acc[j][i] = 0.f;

  const float* xb = x + ((size_t)n << 21);

  if (y == 0) {
    for (int t2 = tl; t2 < 256; t2 += 128) Asb[t2] = 0.f;
  }
  if (y == 63) {
    for (int t2 = tl; t2 < 256; t2 += 128) Asb[512 + t2] = 0.f;
  }

  int wv = tl >> 6;
  int lane = tl & 63;
  int lrow = lane >> 5;
  int lcol = (lane & 31) << 2;
  int aci = lane >> 4;
  int aoff = (lane & 15) << 2;

  for (int cc = 0; cc < 256; cc += 4) {
    int ci0 = cibase + cc;
    for (int yr = wv; yr < 3; yr += 2) {
      int ys = y + yr - 1;
      if (ys >= 0 && ys < 64) {
        const float* g =
            xb + (((size_t)(ci0 + aci)) << 12) + (ys << 6) + aoff;
        load_lds16(g, &Asb[yr << 8]);
      }
    }
    for (int i = 0; i < 9; i++) {
      int r0 = i * 4 + wv * 2;
      int row = r0 + lrow;
      int kk = row >> 2, ci = row & 3;
      const float* g = wt + (((size_t)(kk << 9)) + ci0 + ci) * 512 + co0 + lcol;
      load_lds16(g, &Bsb[r0 << 7]);
    }
    __syncthreads();
    for (int k = 0; k < 4; k++) {
#pragma unroll
      for (int ky = 0; ky < 3; ky++) {
        const float* arr = &Asb[((ky << 2) + k) << 6];
        float w10[10];
        w10[0] = (tx == 0) ? 0.f : arr[x0 - 1];
        float4 a0 = *(const float4*)&arr[x0];
        float4 a1 = *(const float4*)&arr[x0 + 4];
        w10[1] = a0.x; w10[2] = a0.y; w10[3] = a0.z; w10[4] = a0.w;
        w10[5] = a1.x; w10[6] = a1.y; w10[7] = a1.z; w10[8] = a1.w;
        w10[9] = (tx == 7) ? 0.f : arr[x0 + 8];
#pragma unroll
        for (int kx = 0; kx < 3; kx++) {
          int kk = ky * 3 + kx;
          const float* br = &Bsb[(((kk << 2) + k) << 7) + (ty << 3)];
          float4 b0 = *(const float4*)br;
          float4 b1 = *(const float4*)(br + 4);
          float bb[8] = {b0.x, b0.y, b0.z, b0.w, b1.x, b1.y, b1.z, b1.w};
#pragma unroll
          for (int j = 0; j < 8; j++)
#pragma unroll
            for (int dx = 0; dx < 8; dx++)
              acc[j][dx] = fmaf(w10[kx + dx], bb[j], acc[j][dx]);
        }
      }
    }
    __syncthreads();
  }

  if (team == 1) {
#pragma unroll
    for (int j = 0; j < 8; j++) {
      *(float4*)&smem[tl * 68 + (j << 3)] = *(float4*)&acc[j][0];
      *(float4*)&smem[tl * 68 + (j << 3) + 4] = *(float4*)&acc[j][4];
    }
  }
  __syncthreads();
  if (team == 0) {
#pragma unroll
    for (int j = 0; j < 8; j++) {
      int co = co0 + (ty << 3) + j;
      float bv = bias[co];
      float4 p0 = *(float4*)&smem[tl * 68 + (j << 3)];
      float4 p1 = *(float4*)&smem[tl * 68 + (j << 3) + 4];
      float4 v0, v1;
      v0.x = fmaxf((acc[j][0] + p0.x) + bv, 0.f);
      v0.y = fmaxf((acc[j][1] + p0.y) + bv, 0.f);
      v0.z = fmaxf((acc[j][2] + p0.z) + bv, 0.f);
      v0.w = fmaxf((acc[j][3] + p0.w) + bv, 0.f);
      v1.x = fmaxf((acc[j][4] + p1.x) + bv, 0.f);
      v1.y = fmaxf((acc[j][5] + p1.y) + bv, 0.f);
      v1.z = fmaxf((acc[j][6] + p1.z) + bv, 0.f);
      v1.w = fmaxf((acc[j][7] + p1.w) + bv, 0.f);
      float* o = &hout[(((size_t)(n * 512 + co)) << 12) + (y << 6) + x0];
      *(float4*)o = v0;
      *(float4*)(o + 4) = v1;
    }
  }
}

// =====================================================================
// heads v2 (proven): tiled GEMM M=64p x N=54 x K=512.
// =====================================================================
__global__ __launch_bounds__(256) void heads_kernel(
    const float* __restrict__ h, const float* __restrict__ w54p,
    const float* __restrict__ loc_b, const float* __restrict__ score_b,
    float* __restrict__ out) {
  __shared__ __align__(16) float hs[32 * 64];
  __shared__ __align__(16) float wsd[32 * 64];
  __shared__ float sacc[64 * 65];
  int n = blockIdx.x >> 6;
  int p0 = (blockIdx.x & 63) << 6;
  int tid = threadIdx.x;
  int txp = tid & 63;
  int tw = tid >> 6;
  float acc[16];
#pragma unroll
  for (int j = 0; j < 16; j++) acc[j] = 0.f;
  const float* hb = h + ((size_t)n * 512) * 4096 + p0;
  for (int k0 = 0; k0 < 512; k0 += 32) {
    for (int t = tid; t < 512; t += 256) {
      int r = t >> 4, l = (t & 15) << 2;
      *(float4*)&hs[(r << 6) + l] =
          *(const float4*)&hb[(((size_t)(k0 + r)) << 12) + l];
      *(float4*)&wsd[(r << 6) + l] =
          *(const float4*)&w54p[((k0 + r) << 6) + l];
    }
    __syncthreads();
    for (int k = 0; k < 32; k++) {
      float hv = hs[(k << 6) + txp];
      const float* wr = &wsd[(k << 6) + (tw << 4)];
#pragma unroll
      for (int u = 0; u < 4; u++) {
        float4 wv = *(const float4*)(wr + (u << 2));
        acc[u * 4 + 0] = fmaf(hv, wv.x, acc[u * 4 + 0]);
        acc[u * 4 + 1] = fmaf(hv, wv.y, acc[u * 4 + 1]);
        acc[u * 4 + 2] = fmaf(hv, wv.z, acc[u * 4 + 2]);
        acc[u * 4 + 3] = fmaf(hv, wv.w, acc[u * 4 + 3]);
      }
    }
    __syncthreads();
  }
#pragma unroll
  for (int j = 0; j < 16; j++) sacc[(tw * 16 + j) * 65 + txp] = acc[j];
  __syncthreads();
  for (int t = tid; t < 64 * 54; t += 256) {
    int p = t / 54, c = t - p * 54;
    float v = sacc[c * 65 + p];
    int gp = (n << 12) + p0 + p;
    if (c < 36) out[LOCS_OFF + (size_t)gp * 36 + c] = v + loc_b[c];
    else out[SCORES_OFF + (size_t)gp * 18 + (c - 36)] = v + score_b[c - 36];
  }
}

// =====================================================================
// Decode (anchors fused + hist fused; valid-only hist atomics, R5)
// =====================================================================
__global__ void decode_kernel(const float* __restrict__ out_ro,
                              const int* __restrict__ pimh,
                              const int* __restrict__ pimw,
                              float* __restrict__ boxes,
                              unsigned long long* __restrict__ keys,
                              unsigned int* __restrict__ hist,
                              float* __restrict__ out) {
  int t = blockIdx.x * 256 + threadIdx.x;
  int n = t / NANCH, k = t - n * NANCH;
  float imh = (float)pimh[0], imw = (float)pimw[0];

  int a = k % 9, pos = k / 9;
  int jj = pos & 63, ii = pos >> 6;
  int ridx = a / 3, sidx = a % 3;
  double r = (ridx == 0) ? 0.5 : ((ridx == 1) ? 1.0 : 2.0);
  double s = (sidx == 0) ? 8.0 : ((sidx == 1) ? 16.0 : 32.0);
  double ahh = 16.0 * s * sqrt(r);
  double aww = 16.0 * s * sqrt(1.0 / r);
  float b0 = (float)(8.0 - ahh / 2.0), b1 = (float)(8.0 - aww / 2.0);
  float b2 = (float)(8.0 + ahh / 2.0), b3 = (float)(8.0 + aww / 2.0);
  float sy = (float)(ii * 16), sx = (float)(jj * 16);
  float a0 = sy + b0, a1 = sx + b1, a2 = sy + b2, a3 = sx + b3;
  if (n == 0) {
    float* o = out + ANCH_OFF + (size_t)k * 4;
    o[0] = a0; o[1] = a1; o[2] = a2; o[3] = a3;
  }

  const float* loc = out_ro + LOCS_OFF + (size_t)t * 4;
  const float* sc = out_ro + SCORES_OFF + (size_t)t * 2;
  float ah = __fsub_rn(a2, a0), aw = __fsub_rn(a3, a1);
  float acy = __fadd_rn(a0, 0.5f * ah), acx = __fadd_rn(a1, 0.5f * aw);
  float dy = loc[0], dx = loc[1], dh = loc[2], dw = loc[3];
  float cy = __fadd_rn(__fmul_rn(dy, ah), acy);
  float cx = __fadd_rn(__fmul_rn(dx, aw), acx);
  float hh = __fmul_rn(expf(dh), ah);
  float ww = __fmul_rn(expf(dw), aw);
  float y1 = __fsub_rn(cy, 0.5f * hh), x1 = __fsub_rn(cx, 0.5f * ww);
  float y2 = __fadd_rn(cy, 0.5f * hh), x2 = __fadd_rn(cx, 0.5f * ww);
  y1 = fminf(fmaxf(y1, 0.f), imh); x1 = fminf(fmaxf(x1, 0.f), imw);
  y2 = fminf(fmaxf(y2, 0.f), imh); x2 = fminf(fmaxf(x2, 0.f), imw);
  bool valid = (__fsub_rn(y2, y1) >= 16.f) && (__fsub_rn(x2, x1) >= 16.f);
  float s0 = sc[0], s1 = sc[1];
  float m = fmaxf(s0, s1);
  float e0 = expf(__fsub_rn(s0, m)), e1 = expf(__fsub_rn(s1, m));
  float fg = __fdiv_rn(e1, __fadd_rn(e0, e1));
  float score = valid ? fg : -INFINITY;
  unsigned int u = __float_as_uint(score);
  unsigned int ord = (u & 0x80000000u) ? ~u : (u | 0x80000000u);
  unsigned long long key =
      ((unsigned long long)(~ord) << 16) | (unsigned long long)(k & 0xFFFF);
  float4 b4; b4.x = y1; b4.y = x1; b4.z = y2; b4.w = x2;
  *(float4*)(boxes + (size_t)t * 4) = b4;
  keys[t] = key;
  if (valid)
    atomicAdd(&hist[((size_t)n << 16) + (unsigned int)(key >> 32)], 1u);
}

// =====================================================================
// Full exclusive prefix over 65536 buckets (per batch), uint4-vectorized
// =====================================================================
__global__ __launch_bounds__(1024) void scanfull_kernel(
    const unsigned int* __restrict__ hist, unsigned int* __restrict__ prefix,
    unsigned int* __restrict__ prefix_mut) {
  int n = blockIdx.x;
  const uint4* h4 = (const uint4*)(hist + ((size_t)n << 16));
  uint4* pf4 = (uint4*)(prefix + ((size_t)n << 16));
  uint4* pm4 = (uint4*)(prefix_mut + ((size_t)n << 16));
  __shared__ unsigned int ps[1024];
  int tid = threadIdx.x;
  int base4 = tid << 4;
  uint4 vals[16];
  unsigned int s = 0;
#pragma unroll
  for (int i = 0; i < 16; i++) {
    vals[i] = h4[base4 + i];
    s += vals[i].x + vals[i].y + vals[i].z + vals[i].w;
  }
  ps[tid] = s;
  __syncthreads();
  for (int off = 1; off < 1024; off <<= 1) {
    unsigned int v = ps[tid];
    unsigned int add = (tid >= off) ? ps[tid - off] : 0u;
    __syncthreads();
    ps[tid] = v + add;
    __syncthreads();
  }
  unsigned int run = ps[tid] - s;
#pragma unroll
  for (int i = 0; i < 16; i++) {
    uint4 hv = vals[i];
    uint4 pv;
    pv.x = run; run += hv.x;
    pv.y = run; run += hv.y;
    pv.z = run; run += hv.z;
    pv.w = run; run += hv.w;
    pf4[base4 + i] = pv;
    pm4[base4 + i] = pv;
  }
}

// =====================================================================
// Scatter into bucket-sorted order (skip invalid keys, R5)
// =====================================================================
__global__ void scatter_kernel(const unsigned long long* __restrict__ keys,
                               unsigned int* __restrict__ prefix_mut,
                               unsigned long long* __restrict__ sorted) {
  int t = blockIdx.x * 256 + threadIdx.x;
  int n = t / NANCH;
  unsigned long long key = keys[t];
  unsigned int b = (unsigned int)(key >> 32);
  if (b >= 0xFF80u) return;          // invalid (-inf) keys: never scattered
  unsigned int pos = atomicAdd(&prefix_mut[((size_t)n << 16) + b], 1u);
  if (pos < 8192) sorted[((size_t)n << 13) + pos] = key;
}

// =====================================================================
// Fixup: exact rank within bucket -> final sorted top-6000 + boxes
// =====================================================================
__global__ void fixup_kernel(const unsigned long long* __restrict__ sorted,
                             const unsigned int* __restrict__ prefix,
                             const unsigned int* __restrict__ hist,
                             const float* __restrict__ boxes,
                             unsigned long long* __restrict__ skeys,
                             float* __restrict__ sboxes) {
  int t = blockIdx.x * 256 + threadIdx.x;
  int n = t / 7168;
  int s = t - n * 7168;
  const unsigned long long* srt = sorted + ((size_t)n << 13);
  unsigned long long key = srt[s];
  unsigned int hi = (unsigned int)(key >> 16);
  if (hi >= 0xFF800000u) {
    if (s < NPRE) skeys[(size_t)n * NPRE + s] = key;
    return;
  }
  unsigned int b = (unsigned int)(key >> 32);
  unsigned int st = prefix[((size_t)n << 16) + b];
  if (st >= (unsigned)NPRE) return;
  unsigned int cnt = hist[((size_t)n << 16) + b];
  unsigned int r = 0;
  if (cnt > 1) {
    for (unsigned int j = 0; j < cnt; j++) r += (srt[st + j] < key) ? 1u : 0u;
  }
  unsigned int pos = st + r;
  if (pos < (unsigned)NPRE) {
    skeys[(size_t)n * NPRE + pos] = key;
    int k = (int)(key & 0xFFFFull);
    float4 bx = *(const float4*)(boxes + (((size_t)n * NANCH) + k) * 4);
    *(float4*)(sboxes + ((size_t)n * NPRE + pos) * 4) = bx;
  }
}

// =====================================================================
// NMS phase A: upper-triangle pairwise suppression bitmask (R3-proven)
// =====================================================================
__global__ __launch_bounds__(64) void nms_mask_kernel(
    const float* __restrict__ sboxes,
    const unsigned long long* __restrict__ skeys,
    unsigned long long* __restrict__ vmask,
    unsigned long long* __restrict__ mask) {
  int n = blockIdx.z;
  int ib = blockIdx.x, jb = blockIdx.y;
  if (jb < ib) return;
  int lane = threadIdx.x;
  __shared__ __align__(16) float jbox[64][4];
  int j = jb * 64 + lane;
  float4 bj4 = (j < NPRE)
                   ? *(const float4*)(sboxes + ((size_t)n * NPRE + j) * 4)
                   : float4{0.f, 0.f, 0.f, 0.f};
  *(float4*)jbox[lane] = bj4;
  __syncthreads();
  if (jb == ib) {
    int idx = ib * 64 + lane;
    bool ok = false;
    if (idx < NPRE) {
      unsigned int khi = (unsigned int)(skeys[(size_t)n * NPRE + idx] >> 16);
      ok = khi < 0xFF800000u;
    }
    unsigned long long m = __ballot(ok);
    if (lane == 0) vmask[(size_t)n * 94 + ib] = m;
  }
  int i = ib * 64 + lane;
  if (i >= NPRE) return;
  float4 bi = *(const float4*)(sboxes + ((size_t)n * NPRE + i) * 4);
  float ay1 = bi.x, ax1 = bi.y, ay2 = bi.z, ax2 = bi.w;
  float areaA = __fmul_rn(__fsub_rn(ay2, ay1), __fsub_rn(ax2, ax1));
  unsigned long long bits = 0ull;
#pragma unroll 8
  for (int l = 0; l < 64; l++) {
    float4 bj = *(const float4*)jbox[l];
    float ty1 = fmaxf(ay1, bj.x), tx1 = fmaxf(ax1, bj.y);
    float ty2 = fminf(ay2, bj.z), tx2 = fminf(ax2, bj.w);
    float wh0 = fmaxf(__fsub_rn(ty2, ty1), 0.f);
    float wh1 = fmaxf(__fsub_rn(tx2, tx1), 0.f);
    float inter = __fmul_rn(wh0, wh1);
    float areaB = __fmul_rn(__fsub_rn(bj.z, bj.x), __fsub_rn(bj.w, bj.y));
    float den = __fadd_rn(__fsub_rn(__fadd_rn(areaA, areaB), inter), 1e-9f);
    float iou = __fdiv_rn(inter, den);
    if (iou > 0.7f) bits |= (1ull << l);
  }
  mask[((size_t)n * NPRE + i) * 94 + jb] = bits;
}

// =====================================================================
// NMS phase B (R13-proven): CONCURRENT warm + serial greedy loop.
// Do not add in-loop load-consuming state (R9 lesson).
// =====================================================================
#define WARM_ROWS 4096

__global__ __launch_bounds__(1024) void nms_reduce_kernel(
    const unsigned long long* __restrict__ mask,
    const unsigned long long* __restrict__ vmask,
    const float* __restrict__ sboxes, float* __restrict__ out) {
  int n = blockIdx.x;
  __shared__ int kept[NPOST];

  if (threadIdx.x >= 64) {
    // ---- concurrent L2 warm (waves 1..15): read-only, no barrier ----
    const ulonglong2* m2 =
        (const ulonglong2*)(mask + (size_t)n * NPRE * 94);
    unsigned long long accw = 0;
    const int total = WARM_ROWS * 94 / 2;    // 192512 x 16B = 3.08 MB
    for (int i = threadIdx.x - 64; i < total; i += 960) {
      ulonglong2 v = m2[i];
      accw ^= v.x ^ v.y;
    }
    asm volatile("" :: "v"(accw));           // keep loads live (rule #17)
    return;
  }

  int lane = threadIdx.x;

  unsigned long long rlo = ~vmask[(size_t)n * 94 + lane];
  unsigned long long rhi = (64 + lane < 94) ? ~vmask[(size_t)n * 94 + 64 + lane]
                                            : ~0ull;
  int count = 0;
  for (int c = 0; c < 94 && count < NPOST; c++) {
    unsigned long long curw =
        (c < 64) ? __shfl(rlo, c) : __shfl(rhi, c - 64);
    unsigned long long cand = ~curw;
    while (cand != 0ull && count < NPOST) {
      int b = __builtin_ctzll(cand);
      int i = c * 64 + b;
      if (lane == 0) kept[count] = i;
      count++;
      const unsigned long long* row = mask + ((size_t)n * NPRE + i) * 94;
      unsigned long long r0 = row[lane];
      unsigned long long r1 = (64 + lane < 94) ? row[64 + lane] : 0ull;
      rlo |= r0; rhi |= r1;
      curw = (c < 64) ? __shfl(rlo, c) : __shfl(rhi, c - 64);
      cand = ~curw;
      cand &= (b == 63) ? 0ull : (~0ull << (b + 1));
    }
  }

  float* rois = out + ROIS_OFF + (size_t)n * NPOST * 4;
  float* ridx = out + RIDX_OFF + (size_t)n * NPOST;
  for (int s = lane; s < NPOST; s += 64) {
    float4 v = {0.f, 0.f, 0.f, 0.f};
    if (s < count) {
      int i = kept[s];
      v = *(const float4*)(sboxes + ((size_t)n * NPRE + i) * 4);
    }
    *(float4*)(rois + (size_t)s * 4) = v;
    ridx[s] = (float)n;
  }
}

// =====================================================================
extern "C" void kernel_launch(void* const* d_in, const int* in_sizes, int n_in,
                              void* d_out, int out_size, void* d_ws,
                              size_t ws_size, hipStream_t stream) {
  const float* feat = (const float*)d_in[0];
  const float* w1 = (const float*)d_in[1];
  const float* b1 = (const float*)d_in[2];
  const float* sw = (const float*)d_in[3];
  const float* sb = (const float*)d_in[4];
  const float* lw = (const float*)d_in[5];
  const float* lb = (const float*)d_in[6];
  const int* pimh = (const int*)d_in[7];
  const int* pimw = (const int*)d_in[8];
  float* out = (float*)d_out;
  char* ws = (char*)d_ws;

  float* wt = (float*)(ws + WT_OFF);
  _Float16* wth = (_Float16*)(ws + WTH_OFF);
  _Float16* wtl = (_Float16*)(ws + WTL_OFF);
  _Float16* xth = (_Float16*)(ws + XTH_OFF);
  _Float16* xtl = (_Float16*)(ws + XTL_OFF);
  float* w54p = (float*)(ws + W54_OFF);
  float* hbuf = (float*)(ws + H_OFF);
  float* boxes = (float*)(ws + BOXES_OFF);
  unsigned long long* keys = (unsigned long long*)(ws + KEYS_OFF);
  unsigned int* hist = (unsigned int*)(ws + HIST_OFF);
  unsigned int* prefix = (unsigned int*)(ws + PREFIX_OFF);
  unsigned int* prefix_mut = (unsigned int*)(ws + PREFIXM_OFF);
  unsigned long long* sorted = (unsigned long long*)(ws + SORTED_OFF);
  unsigned long long* skeys = (unsigned long long*)(ws + SKEYS_OFF);
  float* sboxes = (float*)(ws + SBOXES_OFF);
  unsigned long long* vmask = (unsigned long long*)(ws + VMASK_OFF);
  unsigned long long* nmask = (unsigned long long*)(ws + MASK_OFF);

  hipMemsetAsync(ws + HIST_OFF, 0, 524288, stream);
  // sentinel-fill sorted[]: unwritten slots read as key >= 0xFF800000...
  hipMemsetAsync(ws + SORTED_OFF, 0xFF, 131072, stream);

  bool big = (ws_size >= WS_NEED_MFMA);
  if (big) {
    prepall_kernel<<<800, 1024, 0, stream>>>(w1, wth, wtl, lw, sw, w54p,
                                             feat, xth, xtl);
    conv1_mfma_kernel<<<dim3(128, 4), 256, 0, stream>>>(xth, xtl, wth, wtl,
                                                        b1, hbuf);
  } else {
    prep_kernel<<<288, 1024, 0, stream>>>(w1, wt, lw, sw, w54p);
    conv1_kernel<<<dim3(128, 4), 256, 0, stream>>>(feat, wt, b1, hbuf);
  }
  heads_kernel<<<128, 256, 0, stream>>>(hbuf, w54p, lb, sb, out);
  decode_kernel<<<288, 256, 0, stream>>>(out, pimh, pimw, boxes, keys, hist,
                                         out);
  scanfull_kernel<<<2, 1024, 0, stream>>>(hist, prefix, prefix_mut);
  scatter_kernel<<<288, 256, 0, stream>>>(keys, prefix_mut, sorted);
  fixup_kernel<<<56, 256, 0, stream>>>(sorted, prefix, hist, boxes, skeys,
                                       sboxes);
  nms_mask_kernel<<<dim3(94, 94, 2), 64, 0, stream>>>(sboxes, skeys, vmask,
                                                      nmask);
  nms_reduce_kernel<<<2, 1024, 0, stream>>>(nmask, vmask, sboxes, out);
}

// Round 16
// 597.053 us; speedup vs baseline: 1.0407x; 1.0153x over previous
//
#include <hip/hip_runtime.h>
#include <cmath>

#define NANCH 36864
#define NPRE 6000
#define NPOST 300

// ---- output (float) offsets ----
#define LOCS_OFF   0
#define SCORES_OFF 294912
#define ROIS_OFF   442368
#define RIDX_OFF   444768
#define ANCH_OFF   445368

// ---- workspace byte offsets ----
#define WT_OFF      0ull          // fallback: 9*512*512*4 = 9437184 fp32 wt
#define WTH_OFF     0ull          // mfma: f16 hi 9*512*512*2 = 4718592
#define WTL_OFF     4718592ull    // mfma: f16 lo (scaled 2^10)
#define PREFIX_OFF  2097152ull    // 2*65536*4 (inside dead WT region)
#define PREFIXM_OFF 2621440ull
#define SORTED_OFF  3145728ull
#define MASK_OFF    0ull          // reuse after fixup
#define H_OFF       9437184ull    // 2*512*4096*4  = 16777216
#define BOXES_OFF   26214400ull
#define W54_OFF     26214400ull
#define KEYS_OFF    27394048ull
#define HIST_OFF    27983872ull
#define SKEYS_OFF   28631168ull
#define SBOXES_OFF  28727168ull
#define VMASK_OFF   29033856ull
// MFMA-path extra regions (only if ws_size >= 46137344):
#define XTH_OFF     29360128ull   // x f16 hi: 2*64*16*64*32*2 = 8388608
#define XTL_OFF     37748736ull   // x f16 lo (scaled 2^10)
#define WS_NEED_MFMA 46137344ull

typedef _Float16 half8 __attribute__((ext_vector_type(8)));
typedef float floatx4 __attribute__((ext_vector_type(4)));

__device__ __forceinline__ void load_lds16(const float* g, float* l) {
#if __has_builtin(__builtin_amdgcn_global_load_lds)
  __builtin_amdgcn_global_load_lds(
      (const __attribute__((address_space(1))) void*)g,
      (__attribute__((address_space(3))) void*)l, 16, 0, 0);
#else
  int lane = threadIdx.x & 63;
  float4 v = *(const float4*)g;
  *(float4*)((char*)l + lane * 16) = v;
#endif
}

__device__ __forceinline__ void load_lds16g(const void* g, void* l) {
#if __has_builtin(__builtin_amdgcn_global_load_lds)
  __builtin_amdgcn_global_load_lds(
      (const __attribute__((address_space(1))) void*)g,
      (__attribute__((address_space(3))) void*)l, 16, 0, 0);
#else
  int lane = threadIdx.x & 63;
  float4 v = *(const float4*)g;
  *(float4*)((char*)l + lane * 16) = v;
#endif
}

// =====================================================================
// prep (FALLBACK path): fused weight transposes (R10/R11-verified)
// =====================================================================
__global__ __launch_bounds__(1024) void prep_kernel(
    const float* __restrict__ w, float* __restrict__ wt,
    const float* __restrict__ lw, const float* __restrict__ sw,
    float* __restrict__ w54p) {
  __shared__ float lds[9][32][33];
  if (blockIdx.x < 256) {
    int tx = threadIdx.x & 31;
    int ty = threadIdx.x >> 5;
    int ci0 = (blockIdx.x & 15) * 32;
    int co0 = (blockIdx.x >> 4) * 32;
    const float* src = w + ((size_t)(co0 + ty) * 512 + (ci0 + tx)) * 9;
#pragma unroll
    for (int k = 0; k < 9; k++) lds[k][tx][ty] = src[k];
    __syncthreads();
#pragma unroll
    for (int k = 0; k < 9; k++) {
      wt[((size_t)k * 512 + (ci0 + ty)) * 512 + co0 + tx] = lds[k][ty][tx];
    }
  } else {
    int t = (blockIdx.x - 256) * 1024 + threadIdx.x;
    int k = t >> 6, co = t & 63;
    float v = 0.f;
    if (co < 36) v = lw[(size_t)co * 512 + k];
    else if (co < 54) v = sw[(size_t)(co - 36) * 512 + k];
    w54p[t] = v;
  }
}

// =====================================================================
// prepall (MFMA path, R14 + R15): prep16 + prepx merged; R15 also
// folds the two hipMemsetAsync dispatches (hist zero + sorted
// sentinel) into the prepx blocks' spare threads — 2 fewer graph
// dispatches; hist consumed 3 dispatches later (decode), sorted 5
// later (scatter): stream order guarantees visibility.
// =====================================================================
__global__ __launch_bounds__(1024) void prepall_kernel(
    const float* __restrict__ w, _Float16* __restrict__ wth,
    _Float16* __restrict__ wtl, const float* __restrict__ lw,
    const float* __restrict__ sw, float* __restrict__ w54p,
    const float* __restrict__ x, _Float16* __restrict__ xth,
    _Float16* __restrict__ xtl, unsigned int* __restrict__ hist,
    unsigned long long* __restrict__ sorted) {
  __shared__ float xs[4][32][65];
  if (blockIdx.x < 512) {
    // ---- R15: inline memsets (one op per thread, first blocks) ----
    int gt = blockIdx.x * 1024 + threadIdx.x;     // 0..524287
    if (gt < 131072) hist[gt] = 0u;               // 2*65536 uints
    else if (gt < 147456) sorted[gt - 131072] = ~0ull;  // 2*8192 u64
    // ---- prepx: 4 tiles per block, one per 256-thread sub-block ----
    int sub = threadIdx.x >> 8;
    int tid = threadIdx.x & 255;
    int b = blockIdx.x * 4 + sub;          // 0..2047
    int cs = b & 15, ny = b >> 4;
    int n = ny >> 6, y = ny & 63;
    const float* xb = x + ((size_t)n << 21) + (y << 6);
#pragma unroll
    for (int p = 0; p < 8; p++) {
      int c = p * 4 + (tid >> 6);
      xs[sub][c][tid & 63] = xb[((size_t)(cs * 32 + c) << 12) + (tid & 63)];
    }
    __syncthreads();
    int px = tid & 63, gx = tid >> 6;      // 4 groups x 64 px
    unsigned int hw[4], lw2[4];
#pragma unroll
    for (int j = 0; j < 4; j++) {
      float v0 = xs[sub][gx * 8 + 2 * j][px];
      float v1 = xs[sub][gx * 8 + 2 * j + 1][px];
      _Float16 h0 = (_Float16)v0, h1 = (_Float16)v1;
      _Float16 l0 = (_Float16)((v0 - (float)h0) * 1024.f);
      _Float16 l1 = (_Float16)((v1 - (float)h1) * 1024.f);
      hw[j] = (unsigned int)__builtin_bit_cast(unsigned short, h0) |
              ((unsigned int)__builtin_bit_cast(unsigned short, h1) << 16);
      lw2[j] = (unsigned int)__builtin_bit_cast(unsigned short, l0) |
               ((unsigned int)__builtin_bit_cast(unsigned short, l1) << 16);
    }
    size_t o = (size_t)b * 2048 + (size_t)gx * 512 + (size_t)px * 8;
    uint4 hv; hv.x = hw[0]; hv.y = hw[1]; hv.z = hw[2]; hv.w = hw[3];
    uint4 lv; lv.x = lw2[0]; lv.y = lw2[1]; lv.z = lw2[2]; lv.w = lw2[3];
    *(uint4*)(xth + o) = hv;
    *(uint4*)(xtl + o) = lv;
  } else if (blockIdx.x < 768) {
    // ---- prep16 weight part (old blocks 0..255) ----
    int bx = blockIdx.x - 512;
    int tx = threadIdx.x & 31;             // ci within 32-block
    int ty = threadIdx.x >> 5;             // co within 32-block
    int ci0 = (bx & 15) * 32;
    int co0 = (bx >> 4) * 32;
    int ci = ci0 + tx, co = co0 + ty;
    const float* src = w + ((size_t)co * 512 + ci) * 9;
    int cot = co >> 7, coin = co & 127;
    int cs = ci >> 5, gg = (ci >> 3) & 3, cii = ci & 7;
    size_t obase = ((((size_t)cot) * 16 + cs) * 4 + gg) * 1024 +
                   (size_t)coin * 8 + cii;
#pragma unroll
    for (int k = 0; k < 9; k++) {
      float v = src[k];
      _Float16 h = (_Float16)v;
      _Float16 l = (_Float16)((v - (float)h) * 1024.f);
      size_t o = (size_t)k * 262144 + obase;
      wth[o] = h;
      wtl[o] = l;
    }
  } else {
    // ---- prep16 w54p tail (old blocks 256..287) ----
    int t = (blockIdx.x - 768) * 1024 + threadIdx.x;   // < 32768
    int k = t >> 6, co = t & 63;
    float v = 0.f;
    if (co < 36) v = lw[(size_t)co * 512 + k];
    else if (co < 54) v = sw[(size_t)(co - 36) * 512 + k];
    w54p[t] = v;
  }
}

// =====================================================================
// conv1 MFMA (R10-proven, ~133us): f16x3 split precision, W staged via
// LDS, R9 conflict-free layouts. AT ITS LDS-BW ROOFLINE for this tile
// config: 12 waves x 12 ds_read_b128/tap = 1152 clk LDS demand/CU at
// 128B/clk peak vs 360 clk MFMA -> MfmaUtil cap ~31-36% (measured 36).
// =====================================================================
__global__ __launch_bounds__(256, 3) void conv1_mfma_kernel(
    const _Float16* __restrict__ xth, const _Float16* __restrict__ xtl,
    const _Float16* __restrict__ wth, const _Float16* __restrict__ wtl,
    const float* __restrict__ bias, float* __restrict__ hout) {
  __shared__ __align__(16) _Float16 sXh[6336];   // [3 yr][4 g][66 row][8]
  __shared__ __align__(16) _Float16 sXl[6336];
  __shared__ __align__(16) _Float16 sWh[4096];   // [4 g][128 co][8]
  __shared__ __align__(16) _Float16 sWl[4096];
  int mb = blockIdx.x;
  int n = mb >> 6, y = mb & 63;
  int co0 = blockIdx.y << 7;
  int tid = threadIdx.x;
  int wv = tid >> 6, lane = tid & 63;
  int m15 = lane & 15, g = lane >> 4;

  floatx4 accm[2][4], accl[2][4];
#pragma unroll
  for (int ct = 0; ct < 2; ct++)
#pragma unroll
    for (int pt = 0; pt < 4; pt++) {
      accm[ct][pt] = (floatx4){0.f, 0.f, 0.f, 0.f};
      accl[ct][pt] = (floatx4){0.f, 0.f, 0.f, 0.f};
    }

  // zero X LDS once: pad rows 0/65 of each g-group + invalid-yr slices
  for (int t2 = tid; t2 < 3168; t2 += 256) {
    ((unsigned int*)sXh)[t2] = 0u;
    ((unsigned int*)sXl)[t2] = 0u;
  }
  __syncthreads();

  bool yv0 = (y > 0), yv2 = (y < 63);
  int p = wv >> 1, hf = wv & 1;
  _Float16* wdst = p ? sWl : sWh;
  const _Float16* wsel = p ? wtl : wth;

  for (int cs = 0; cs < 16; cs++) {
    // ---- X DMA: 24 wave-DMAs (6/wave): (yr, part, g) x 1KB linear ----
    {
      int base = wv * 6;
#pragma unroll
      for (int i = 0; i < 6; i++) {
        int idx = base + i;                 // 0..23
        int yr = idx >> 3, rem = idx & 7;
        int part = rem >> 2, d = rem & 3;   // d = g-group
        int ys = y + yr - 1;
        if (ys >= 0 && ys < 64) {           // wave-uniform
          const _Float16* s =
              (part ? xtl : xth) +
              ((((size_t)(n * 64 + ys)) * 16 + cs) << 11) + (d << 9) +
              (lane << 3);
          _Float16* dst = (part ? sXl : sXh) + yr * 2112 + d * 528 + 8;
          load_lds16g(s, dst);
        }
      }
    }
    // W tile base for this (co-tile, cs): [4 g][128 co][8] contiguous
    size_t woff0 = (size_t)(co0 >> 7) * 65536 + (size_t)cs * 4096;
    const _Float16* wsrc0 = wsel + woff0 + (lane << 3);
#pragma unroll
    for (int tap = 0; tap < 9; tap++) {
      int ky = tap / 3;
      int kx = tap - ky * 3;
      if (ky == 0 && !yv0) continue;        // block-uniform: zero slice
      if (ky == 2 && !yv2) continue;
      // ---- W DMA: wave (p,hf) loads g-groups {2hf, 2hf+1}, 4x1KB ----
      const _Float16* ws = wsrc0 + (size_t)tap * 262144;
#pragma unroll
      for (int e = 0; e < 4; e++) {
        int gd = hf * 2 + (e >> 1), half = e & 1;
        load_lds16g(ws + gd * 1024 + half * 512,
                    wdst + gd * 1024 + half * 512);
      }
      __syncthreads();
      // ---- frags (16B lane stride: conflict-free) ----
      half8 Ah[2], Al[2], Bh[4], Bl[4];
#pragma unroll
      for (int ct = 0; ct < 2; ct++) {
        int ao = (g << 10) + (((wv << 5) + (ct << 4) + m15) << 3);
        Ah[ct] = *(const half8*)(sWh + ao);
        Al[ct] = *(const half8*)(sWl + ao);
      }
#pragma unroll
      for (int pt = 0; pt < 4; pt++) {
        int bo = ky * 2112 + g * 528 + (((pt << 4) + m15 + kx) << 3);
        Bh[pt] = *(const half8*)(sXh + bo);
        Bl[pt] = *(const half8*)(sXl + bo);
      }
#pragma unroll
      for (int ct = 0; ct < 2; ct++)
#pragma unroll
        for (int pt = 0; pt < 4; pt++) {
          accm[ct][pt] = __builtin_amdgcn_mfma_f32_16x16x32_f16(
              Ah[ct], Bh[pt], accm[ct][pt], 0, 0, 0);
          accl[ct][pt] = __builtin_amdgcn_mfma_f32_16x16x32_f16(
              Ah[ct], Bl[pt], accl[ct][pt], 0, 0, 0);
          accl[ct][pt] = __builtin_amdgcn_mfma_f32_16x16x32_f16(
              Al[ct], Bh[pt], accl[ct][pt], 0, 0, 0);
        }
      __syncthreads();
    }
  }

#pragma unroll
  for (int ct = 0; ct < 2; ct++)
#pragma unroll
    for (int pt = 0; pt < 4; pt++) {
#pragma unroll
      for (int r = 0; r < 4; r++) {
        int co = co0 + (wv << 5) + (ct << 4) + (g << 2) + r;
        float v = accm[ct][pt][r] + accl[ct][pt][r] * 0.0009765625f +
                  bias[co];
        hout[((size_t)(n * 512 + co) << 12) + (y << 6) + (pt << 4) + m15] =
            fmaxf(v, 0.f);
      }
    }
}

// =====================================================================
// conv1 v9 (FALLBACK, proven): fp32 3x3 512->512 + bias + ReLU.
// =====================================================================
__global__ __launch_bounds__(256) void conv1_kernel(
    const float* __restrict__ x, const float* __restrict__ wt,
    const float* __restrict__ bias, float* __restrict__ hout) {
  __shared__ __align__(16) float smem[10752];
  int mb = blockIdx.x;
  int n = mb >> 6, y = mb & 63;
  int co0 = blockIdx.y << 7;
  int tid = threadIdx.x;
  int team = tid >> 7;
  int tl = tid & 127;
  int cibase = team << 8;
  float* Asb = smem + team * 768;
  float* Bsb = smem + 1536 + team * 4608;
  int tx = tl & 7, ty = tl >> 3;
  int x0 = tx << 3;

  float acc[8][8];
#pragma unroll
  for (int j = 0; j < 8; j++)
#pragma unroll
    for (int i = 0; i < 8; i++) acc[j][i] = 0.f;

  const float* xb = x + ((size_t)n << 21);

  if (y == 0) {
    for (int t2 = tl; t2 < 256; t2 += 128) Asb[t2] = 0.f;
  }
  if (y == 63) {
    for (int t2 = tl; t2 < 256; t2 += 128) Asb[512 + t2] = 0.f;
  }

  int wv = tl >> 6;
  int lane = tl & 63;
  int lrow = lane >> 5;
  int lcol = (lane & 31) << 2;
  int aci = lane >> 4;
  int aoff = (lane & 15) << 2;

  for (int cc = 0; cc < 256; cc += 4) {
    int ci0 = cibase + cc;
    for (int yr = wv; yr < 3; yr += 2) {
      int ys = y + yr - 1;
      if (ys >= 0 && ys < 64) {
        const float* g =
            xb + (((size_t)(ci0 + aci)) << 12) + (ys << 6) + aoff;
        load_lds16(g, &Asb[yr << 8]);
      }
    }
    for (int i = 0; i < 9; i++) {
      int r0 = i * 4 + wv * 2;
      int row = r0 + lrow;
      int kk = row >> 2, ci = row & 3;
      const float* g = wt + (((size_t)(kk << 9)) + ci0 + ci) * 512 + co0 + lcol;
      load_lds16(g, &Bsb[r0 << 7]);
    }
    __syncthreads();
    for (int k = 0; k < 4; k++) {
#pragma unroll
      for (int ky = 0; ky < 3; ky++) {
        const float* arr = &Asb[((ky << 2) + k) << 6];
        float w10[10];
        w10[0] = (tx == 0) ? 0.f : arr[x0 - 1];
        float4 a0 = *(const float4*)&arr[x0];
        float4 a1 = *(const float4*)&arr[x0 + 4];
        w10[1] = a0.x; w10[2] = a0.y; w10[3] = a0.z; w10[4] = a0.w;
        w10[5] = a1.x; w10[6] = a1.y; w10[7] = a1.z; w10[8] = a1.w;
        w10[9] = (tx == 7) ? 0.f : arr[x0 + 8];
#pragma unroll
        for (int kx = 0; kx < 3; kx++) {
          int kk = ky * 3 + kx;
          const float* br = &Bsb[(((kk << 2) + k) << 7) + (ty << 3)];
          float4 b0 = *(const float4*)br;
          float4 b1 = *(const float4*)(br + 4);
          float bb[8] = {b0.x, b0.y, b0.z, b0.w, b1.x, b1.y, b1.z, b1.w};
#pragma unroll
          for (int j = 0; j < 8; j++)
#pragma unroll
            for (int dx = 0; dx < 8; dx++)
              acc[j][dx] = fmaf(w10[kx + dx], bb[j], acc[j][dx]);
        }
      }
    }
    __syncthreads();
  }

  if (team == 1) {
#pragma unroll
    for (int j = 0; j < 8; j++) {
      *(float4*)&smem[tl * 68 + (j << 3)] = *(float4*)&acc[j][0];
      *(float4*)&smem[tl * 68 + (j << 3) + 4] = *(float4*)&acc[j][4];
    }
  }
  __syncthreads();
  if (team == 0) {
#pragma unroll
    for (int j = 0; j < 8; j++) {
      int co = co0 + (ty << 3) + j;
      float bv = bias[co];
      float4 p0 = *(float4*)&smem[tl * 68 + (j << 3)];
      float4 p1 = *(float4*)&smem[tl * 68 + (j << 3) + 4];
      float4 v0, v1;
      v0.x = fmaxf((acc[j][0] + p0.x) + bv, 0.f);
      v0.y = fmaxf((acc[j][1] + p0.y) + bv, 0.f);
      v0.z = fmaxf((acc[j][2] + p0.z) + bv, 0.f);
      v0.w = fmaxf((acc[j][3] + p0.w) + bv, 0.f);
      v1.x = fmaxf((acc[j][4] + p1.x) + bv, 0.f);
      v1.y = fmaxf((acc[j][5] + p1.y) + bv, 0.f);
      v1.z = fmaxf((acc[j][6] + p1.z) + bv, 0.f);
      v1.w = fmaxf((acc[j][7] + p1.w) + bv, 0.f);
      float* o = &hout[(((size_t)(n * 512 + co)) << 12) + (y << 6) + x0];
      *(float4*)o = v0;
      *(float4*)(o + 4) = v1;
    }
  }
}

// =====================================================================
// heads v2 (proven): tiled GEMM M=64p x N=54 x K=512.
// =====================================================================
__global__ __launch_bounds__(256) void heads_kernel(
    const float* __restrict__ h, const float* __restrict__ w54p,
    const float* __restrict__ loc_b, const float* __restrict__ score_b,
    float* __restrict__ out) {
  __shared__ __align__(16) float hs[32 * 64];
  __shared__ __align__(16) float wsd[32 * 64];
  __shared__ float sacc[64 * 65];
  int n = blockIdx.x >> 6;
  int p0 = (blockIdx.x & 63) << 6;
  int tid = threadIdx.x;
  int txp = tid & 63;
  int tw = tid >> 6;
  float acc[16];
#pragma unroll
  for (int j = 0; j < 16; j++) acc[j] = 0.f;
  const float* hb = h + ((size_t)n * 512) * 4096 + p0;
  for (int k0 = 0; k0 < 512; k0 += 32) {
    for (int t = tid; t < 512; t += 256) {
      int r = t >> 4, l = (t & 15) << 2;
      *(float4*)&hs[(r << 6) + l] =
          *(const float4*)&hb[(((size_t)(k0 + r)) << 12) + l];
      *(float4*)&wsd[(r << 6) + l] =
          *(const float4*)&w54p[((k0 + r) << 6) + l];
    }
    __syncthreads();
    for (int k = 0; k < 32; k++) {
      float hv = hs[(k << 6) + txp];
      const float* wr = &wsd[(k << 6) + (tw << 4)];
#pragma unroll
      for (int u = 0; u < 4; u++) {
        float4 wv = *(const float4*)(wr + (u << 2));
        acc[u * 4 + 0] = fmaf(hv, wv.x, acc[u * 4 + 0]);
        acc[u * 4 + 1] = fmaf(hv, wv.y, acc[u * 4 + 1]);
        acc[u * 4 + 2] = fmaf(hv, wv.z, acc[u * 4 + 2]);
        acc[u * 4 + 3] = fmaf(hv, wv.w, acc[u * 4 + 3]);
      }
    }
    __syncthreads();
  }
#pragma unroll
  for (int j = 0; j < 16; j++) sacc[(tw * 16 + j) * 65 + txp] = acc[j];
  __syncthreads();
  for (int t = tid; t < 64 * 54; t += 256) {
    int p = t / 54, c = t - p * 54;
    float v = sacc[c * 65 + p];
    int gp = (n << 12) + p0 + p;
    if (c < 36) out[LOCS_OFF + (size_t)gp * 36 + c] = v + loc_b[c];
    else out[SCORES_OFF + (size_t)gp * 18 + (c - 36)] = v + score_b[c - 36];
  }
}

// =====================================================================
// Decode (anchors fused + hist fused; valid-only hist atomics, R5)
// =====================================================================
__global__ void decode_kernel(const float* __restrict__ out_ro,
                              const int* __restrict__ pimh,
                              const int* __restrict__ pimw,
                              float* __restrict__ boxes,
                              unsigned long long* __restrict__ keys,
                              unsigned int* __restrict__ hist,
                              float* __restrict__ out) {
  int t = blockIdx.x * 256 + threadIdx.x;
  int n = t / NANCH, k = t - n * NANCH;
  float imh = (float)pimh[0], imw = (float)pimw[0];

  int a = k % 9, pos = k / 9;
  int jj = pos & 63, ii = pos >> 6;
  int ridx = a / 3, sidx = a % 3;
  double r = (ridx == 0) ? 0.5 : ((ridx == 1) ? 1.0 : 2.0);
  double s = (sidx == 0) ? 8.0 : ((sidx == 1) ? 16.0 : 32.0);
  double ahh = 16.0 * s * sqrt(r);
  double aww = 16.0 * s * sqrt(1.0 / r);
  float b0 = (float)(8.0 - ahh / 2.0), b1 = (float)(8.0 - aww / 2.0);
  float b2 = (float)(8.0 + ahh / 2.0), b3 = (float)(8.0 + aww / 2.0);
  float sy = (float)(ii * 16), sx = (float)(jj * 16);
  float a0 = sy + b0, a1 = sx + b1, a2 = sy + b2, a3 = sx + b3;
  if (n == 0) {
    float* o = out + ANCH_OFF + (size_t)k * 4;
    o[0] = a0; o[1] = a1; o[2] = a2; o[3] = a3;
  }

  const float* loc = out_ro + LOCS_OFF + (size_t)t * 4;
  const float* sc = out_ro + SCORES_OFF + (size_t)t * 2;
  float ah = __fsub_rn(a2, a0), aw = __fsub_rn(a3, a1);
  float acy = __fadd_rn(a0, 0.5f * ah), acx = __fadd_rn(a1, 0.5f * aw);
  float dy = loc[0], dx = loc[1], dh = loc[2], dw = loc[3];
  float cy = __fadd_rn(__fmul_rn(dy, ah), acy);
  float cx = __fadd_rn(__fmul_rn(dx, aw), acx);
  float hh = __fmul_rn(expf(dh), ah);
  float ww = __fmul_rn(expf(dw), aw);
  float y1 = __fsub_rn(cy, 0.5f * hh), x1 = __fsub_rn(cx, 0.5f * ww);
  float y2 = __fadd_rn(cy, 0.5f * hh), x2 = __fadd_rn(cx, 0.5f * ww);
  y1 = fminf(fmaxf(y1, 0.f), imh); x1 = fminf(fmaxf(x1, 0.f), imw);
  y2 = fminf(fmaxf(y2, 0.f), imh); x2 = fminf(fmaxf(x2, 0.f), imw);
  bool valid = (__fsub_rn(y2, y1) >= 16.f) && (__fsub_rn(x2, x1) >= 16.f);
  float s0 = sc[0], s1 = sc[1];
  float m = fmaxf(s0, s1);
  float e0 = expf(__fsub_rn(s0, m)), e1 = expf(__fsub_rn(s1, m));
  float fg = __fdiv_rn(e1, __fadd_rn(e0, e1));
  float score = valid ? fg : -INFINITY;
  unsigned int u = __float_as_uint(score);
  unsigned int ord = (u & 0x80000000u) ? ~u : (u | 0x80000000u);
  unsigned long long key =
      ((unsigned long long)(~ord) << 16) | (unsigned long long)(k & 0xFFFF);
  float4 b4; b4.x = y1; b4.y = x1; b4.z = y2; b4.w = x2;
  *(float4*)(boxes + (size_t)t * 4) = b4;
  keys[t] = key;
  if (valid)
    atomicAdd(&hist[((size_t)n << 16) + (unsigned int)(key >> 32)], 1u);
}

// =====================================================================
// Full exclusive prefix over 65536 buckets (per batch), uint4-vectorized
// =====================================================================
__global__ __launch_bounds__(1024) void scanfull_kernel(
    const unsigned int* __restrict__ hist, unsigned int* __restrict__ prefix,
    unsigned int* __restrict__ prefix_mut) {
  int n = blockIdx.x;
  const uint4* h4 = (const uint4*)(hist + ((size_t)n << 16));
  uint4* pf4 = (uint4*)(prefix + ((size_t)n << 16));
  uint4* pm4 = (uint4*)(prefix_mut + ((size_t)n << 16));
  __shared__ unsigned int ps[1024];
  int tid = threadIdx.x;
  int base4 = tid << 4;
  uint4 vals[16];
  unsigned int s = 0;
#pragma unroll
  for (int i = 0; i < 16; i++) {
    vals[i] = h4[base4 + i];
    s += vals[i].x + vals[i].y + vals[i].z + vals[i].w;
  }
  ps[tid] = s;
  __syncthreads();
  for (int off = 1; off < 1024; off <<= 1) {
    unsigned int v = ps[tid];
    unsigned int add = (tid >= off) ? ps[tid - off] : 0u;
    __syncthreads();
    ps[tid] = v + add;
    __syncthreads();
  }
  unsigned int run = ps[tid] - s;
#pragma unroll
  for (int i = 0; i < 16; i++) {
    uint4 hv = vals[i];
    uint4 pv;
    pv.x = run; run += hv.x;
    pv.y = run; run += hv.y;
    pv.z = run; run += hv.z;
    pv.w = run; run += hv.w;
    pf4[base4 + i] = pv;
    pm4[base4 + i] = pv;
  }
}

// =====================================================================
// Scatter into bucket-sorted order (skip invalid keys, R5)
// =====================================================================
__global__ void scatter_kernel(const unsigned long long* __restrict__ keys,
                               unsigned int* __restrict__ prefix_mut,
                               unsigned long long* __restrict__ sorted) {
  int t = blockIdx.x * 256 + threadIdx.x;
  int n = t / NANCH;
  unsigned long long key = keys[t];
  unsigned int b = (unsigned int)(key >> 32);
  if (b >= 0xFF80u) return;          // invalid (-inf) keys: never scattered
  unsigned int pos = atomicAdd(&prefix_mut[((size_t)n << 16) + b], 1u);
  if (pos < 8192) sorted[((size_t)n << 13) + pos] = key;
}

// =====================================================================
// Fixup: exact rank within bucket -> final sorted top-6000 + boxes
// =====================================================================
__global__ void fixup_kernel(const unsigned long long* __restrict__ sorted,
                             const unsigned int* __restrict__ prefix,
                             const unsigned int* __restrict__ hist,
                             const float* __restrict__ boxes,
                             unsigned long long* __restrict__ skeys,
                             float* __restrict__ sboxes) {
  int t = blockIdx.x * 256 + threadIdx.x;
  int n = t / 7168;
  int s = t - n * 7168;
  const unsigned long long* srt = sorted + ((size_t)n << 13);
  unsigned long long key = srt[s];
  unsigned int hi = (unsigned int)(key >> 16);
  if (hi >= 0xFF800000u) {
    if (s < NPRE) skeys[(size_t)n * NPRE + s] = key;
    return;
  }
  unsigned int b = (unsigned int)(key >> 32);
  unsigned int st = prefix[((size_t)n << 16) + b];
  if (st >= (unsigned)NPRE) return;
  unsigned int cnt = hist[((size_t)n << 16) + b];
  unsigned int r = 0;
  if (cnt > 1) {
    for (unsigned int j = 0; j < cnt; j++) r += (srt[st + j] < key) ? 1u : 0u;
  }
  unsigned int pos = st + r;
  if (pos < (unsigned)NPRE) {
    skeys[(size_t)n * NPRE + pos] = key;
    int k = (int)(key & 0xFFFFull);
    float4 bx = *(const float4*)(boxes + (((size_t)n * NANCH) + k) * 4);
    *(float4*)(sboxes + ((size_t)n * NPRE + pos) * 4) = bx;
  }
}

// =====================================================================
// NMS phase A: upper-triangle pairwise suppression bitmask (R3-proven)
// =====================================================================
__global__ __launch_bounds__(64) void nms_mask_kernel(
    const float* __restrict__ sboxes,
    const unsigned long long* __restrict__ skeys,
    unsigned long long* __restrict__ vmask,
    unsigned long long* __restrict__ mask) {
  int n = blockIdx.z;
  int ib = blockIdx.x, jb = blockIdx.y;
  if (jb < ib) return;
  int lane = threadIdx.x;
  __shared__ __align__(16) float jbox[64][4];
  int j = jb * 64 + lane;
  float4 bj4 = (j < NPRE)
                   ? *(const float4*)(sboxes + ((size_t)n * NPRE + j) * 4)
                   : float4{0.f, 0.f, 0.f, 0.f};
  *(float4*)jbox[lane] = bj4;
  __syncthreads();
  if (jb == ib) {
    int idx = ib * 64 + lane;
    bool ok = false;
    if (idx < NPRE) {
      unsigned int khi = (unsigned int)(skeys[(size_t)n * NPRE + idx] >> 16);
      ok = khi < 0xFF800000u;
    }
    unsigned long long m = __ballot(ok);
    if (lane == 0) vmask[(size_t)n * 94 + ib] = m;
  }
  int i = ib * 64 + lane;
  if (i >= NPRE) return;
  float4 bi = *(const float4*)(sboxes + ((size_t)n * NPRE + i) * 4);
  float ay1 = bi.x, ax1 = bi.y, ay2 = bi.z, ax2 = bi.w;
  float areaA = __fmul_rn(__fsub_rn(ay2, ay1), __fsub_rn(ax2, ax1));
  unsigned long long bits = 0ull;
#pragma unroll 8
  for (int l = 0; l < 64; l++) {
    float4 bj = *(const float4*)jbox[l];
    float ty1 = fmaxf(ay1, bj.x), tx1 = fmaxf(ax1, bj.y);
    float ty2 = fminf(ay2, bj.z), tx2 = fminf(ax2, bj.w);
    float wh0 = fmaxf(__fsub_rn(ty2, ty1), 0.f);
    float wh1 = fmaxf(__fsub_rn(tx2, tx1), 0.f);
    float inter = __fmul_rn(wh0, wh1);
    float areaB = __fmul_rn(__fsub_rn(bj.z, bj.x), __fsub_rn(bj.w, bj.y));
    float den = __fadd_rn(__fsub_rn(__fadd_rn(areaA, areaB), inter), 1e-9f);
    float iou = __fdiv_rn(inter, den);
    if (iou > 0.7f) bits |= (1ull << l);
  }
  mask[((size_t)n * NPRE + i) * 94 + jb] = bits;
}

// =====================================================================
// NMS phase B (R13-proven): CONCURRENT warm + serial greedy loop.
// Do not add in-loop load-consuming state (R9 lesson).
// =====================================================================
#define WARM_ROWS 4096

__global__ __launch_bounds__(1024) void nms_reduce_kernel(
    const unsigned long long* __restrict__ mask,
    const unsigned long long* __restrict__ vmask,
    const float* __restrict__ sboxes, float* __restrict__ out) {
  int n = blockIdx.x;
  __shared__ int kept[NPOST];

  if (threadIdx.x >= 64) {
    // ---- concurrent L2 warm (waves 1..15): read-only, no barrier ----
    const ulonglong2* m2 =
        (const ulonglong2*)(mask + (size_t)n * NPRE * 94);
    unsigned long long accw = 0;
    const int total = WARM_ROWS * 94 / 2;    // 192512 x 16B = 3.08 MB
    for (int i = threadIdx.x - 64; i < total; i += 960) {
      ulonglong2 v = m2[i];
      accw ^= v.x ^ v.y;
    }
    asm volatile("" :: "v"(accw));           // keep loads live (rule #17)
    return;
  }

  int lane = threadIdx.x;

  unsigned long long rlo = ~vmask[(size_t)n * 94 + lane];
  unsigned long long rhi = (64 + lane < 94) ? ~vmask[(size_t)n * 94 + 64 + lane]
                                            : ~0ull;
  int count = 0;
  for (int c = 0; c < 94 && count < NPOST; c++) {
    unsigned long long curw =
        (c < 64) ? __shfl(rlo, c) : __shfl(rhi, c - 64);
    unsigned long long cand = ~curw;
    while (cand != 0ull && count < NPOST) {
      int b = __builtin_ctzll(cand);
      int i = c * 64 + b;
      if (lane == 0) kept[count] = i;
      count++;
      const unsigned long long* row = mask + ((size_t)n * NPRE + i) * 94;
      unsigned long long r0 = row[lane];
      unsigned long long r1 = (64 + lane < 94) ? row[64 + lane] : 0ull;
      rlo |= r0; rhi |= r1;
      curw = (c < 64) ? __shfl(rlo, c) : __shfl(rhi, c - 64);
      cand = ~curw;
      cand &= (b == 63) ? 0ull : (~0ull << (b + 1));
    }
  }

  float* rois = out + ROIS_OFF + (size_t)n * NPOST * 4;
  float* ridx = out + RIDX_OFF + (size_t)n * NPOST;
  for (int s = lane; s < NPOST; s += 64) {
    float4 v = {0.f, 0.f, 0.f, 0.f};
    if (s < count) {
      int i = kept[s];
      v = *(const float4*)(sboxes + ((size_t)n * NPRE + i) * 4);
    }
    *(float4*)(rois + (size_t)s * 4) = v;
    ridx[s] = (float)n;
  }
}

// =====================================================================
extern "C" void kernel_launch(void* const* d_in, const int* in_sizes, int n_in,
                              void* d_out, int out_size, void* d_ws,
                              size_t ws_size, hipStream_t stream) {
  const float* feat = (const float*)d_in[0];
  const float* w1 = (const float*)d_in[1];
  const float* b1 = (const float*)d_in[2];
  const float* sw = (const float*)d_in[3];
  const float* sb = (const float*)d_in[4];
  const float* lw = (const float*)d_in[5];
  const float* lb = (const float*)d_in[6];
  const int* pimh = (const int*)d_in[7];
  const int* pimw = (const int*)d_in[8];
  float* out = (float*)d_out;
  char* ws = (char*)d_ws;

  float* wt = (float*)(ws + WT_OFF);
  _Float16* wth = (_Float16*)(ws + WTH_OFF);
  _Float16* wtl = (_Float16*)(ws + WTL_OFF);
  _Float16* xth = (_Float16*)(ws + XTH_OFF);
  _Float16* xtl = (_Float16*)(ws + XTL_OFF);
  float* w54p = (float*)(ws + W54_OFF);
  float* hbuf = (float*)(ws + H_OFF);
  float* boxes = (float*)(ws + BOXES_OFF);
  unsigned long long* keys = (unsigned long long*)(ws + KEYS_OFF);
  unsigned int* hist = (unsigned int*)(ws + HIST_OFF);
  unsigned int* prefix = (unsigned int*)(ws + PREFIX_OFF);
  unsigned int* prefix_mut = (unsigned int*)(ws + PREFIXM_OFF);
  unsigned long long* sorted = (unsigned long long*)(ws + SORTED_OFF);
  unsigned long long* skeys = (unsigned long long*)(ws + SKEYS_OFF);
  float* sboxes = (float*)(ws + SBOXES_OFF);
  unsigned long long* vmask = (unsigned long long*)(ws + VMASK_OFF);
  unsigned long long* nmask = (unsigned long long*)(ws + MASK_OFF);

  bool big = (ws_size >= WS_NEED_MFMA);
  if (big) {
    // hist zero + sorted sentinel folded into prepall (R15)
    prepall_kernel<<<800, 1024, 0, stream>>>(w1, wth, wtl, lw, sw, w54p,
                                             feat, xth, xtl, hist, sorted);
    conv1_mfma_kernel<<<dim3(128, 4), 256, 0, stream>>>(xth, xtl, wth, wtl,
                                                        b1, hbuf);
  } else {
    hipMemsetAsync(ws + HIST_OFF, 0, 524288, stream);
    hipMemsetAsync(ws + SORTED_OFF, 0xFF, 131072, stream);
    prep_kernel<<<288, 1024, 0, stream>>>(w1, wt, lw, sw, w54p);
    conv1_kernel<<<dim3(128, 4), 256, 0, stream>>>(feat, wt, b1, hbuf);
  }
  heads_kernel<<<128, 256, 0, stream>>>(hbuf, w54p, lb, sb, out);
  decode_kernel<<<288, 256, 0, stream>>>(out, pimh, pimw, boxes, keys, hist,
                                         out);
  scanfull_kernel<<<2, 1024, 0, stream>>>(hist, prefix, prefix_mut);
  scatter_kernel<<<288, 256, 0, stream>>>(keys, prefix_mut, sorted);
  fixup_kernel<<<56, 256, 0, stream>>>(sorted, prefix, hist, boxes, skeys,
                                       sboxes);
  nms_mask_kernel<<<dim3(94, 94, 2), 64, 0, stream>>>(sboxes, skeys, vmask,
                                                      nmask);
  nms_reduce_kernel<<<2, 1024, 0, stream>>>(nmask, vmask, sboxes, out);
}